// Round 12
// baseline (233.038 us; speedup 1.0000x reference)
//
#include <hip/hip_runtime.h>

#define IMG 512
#define CIN 32
#define COUT 32
#define NORI 8
#define HW (IMG*IMG)

#define TS 16

// ---- K1 staging geometry (halo 1), f16 channel-pair cells ----
#define W1 18
#define WR1 19
#define CHS1 (W1*WR1)      // 342 uints per channel-pair
// ---- K2 staging geometry (halo 4), f16 channel-pair cells ----
#define HALO 4
#define WIN 24
#define WROW 25
#define CHS2 (WIN*WROW)    // 600 uints per channel-pair

typedef _Float16 h2 __attribute__((ext_vector_type(2)));
typedef __fp16  fp16v2 __attribute__((ext_vector_type(2)));

__device__ __forceinline__ float dot2acc(unsigned int a, unsigned int b, float c) {
#if __has_builtin(__builtin_amdgcn_fdot2)
    return __builtin_amdgcn_fdot2(__builtin_bit_cast(h2, a),
                                  __builtin_bit_cast(h2, b), c, false);
#else
    h2 av = __builtin_bit_cast(h2, a), bv = __builtin_bit_cast(h2, b);
    return fmaf((float)av[0], (float)bv[0], fmaf((float)av[1], (float)bv[1], c));
#endif
}

__device__ __forceinline__ unsigned int packh2(float a, float b) {
#if __has_builtin(__builtin_amdgcn_cvt_pkrtz)
    fp16v2 r = __builtin_amdgcn_cvt_pkrtz(a, b);
    return __builtin_bit_cast(unsigned int, r);
#else
    h2 r; r[0] = (_Float16)a; r[1] = (_Float16)b;
    return __builtin_bit_cast(unsigned int, r);
#endif
}

__device__ __forceinline__ unsigned int packh2_rne(float a, float b) {
    h2 r; r[0] = (_Float16)a; r[1] = (_Float16)b;   // RNE casts
    return __builtin_bit_cast(unsigned int, r);
}

__device__ __forceinline__ h2 splat2(float a) {
    _Float16 h = (_Float16)a;
    h2 r; r[0] = h; r[1] = h;
    return r;
}

#define GEMV8(TP, S2) do {                                             \
    const uint4* _tp = (TP);                                           \
    _Pragma("unroll")                                                  \
    for (int q = 0; q < 8; ++q) {                                      \
        uint4 u = _tp[q];                                              \
        oacc[q * 4 + 0] = dot2acc((S2), u.x, oacc[q * 4 + 0]);         \
        oacc[q * 4 + 1] = dot2acc((S2), u.y, oacc[q * 4 + 1]);         \
        oacc[q * 4 + 2] = dot2acc((S2), u.z, oacc[q * 4 + 2]);         \
        oacc[q * 4 + 3] = dot2acc((S2), u.w, oacc[q * 4 + 3]);         \
    }                                                                  \
} while (0)

// tw_h layout (uint = h2 = channel pair): tw_h[((r*9 + k)*(CIN/2) + cp)*COUT + o]
__global__ void build_tw_kernel(const float* __restrict__ weight, unsigned int* __restrict__ tw_h) {
    int idx = blockIdx.x * blockDim.x + threadIdx.x; // 0..511
    if (idx >= COUT * (CIN / 2)) return;
    int o = idx & 31, cp = idx >> 5;

    float bb[2][9], w45[2][9];
    const float cs = 0.70710678f;
#pragma unroll
    for (int h = 0; h < 2; ++h) {
        int c = 2 * cp + h;
#pragma unroll
        for (int t = 0; t < 9; ++t) bb[h][t] = weight[(o * CIN + c) * 9 + t];
#pragma unroll
        for (int i = 0; i < 3; ++i) {
#pragma unroll
            for (int j = 0; j < 3; ++j) {
                float ys = cs * (float)(i - 1) + cs * (float)(j - 1) + 1.0f;
                float xs = -cs * (float)(i - 1) + cs * (float)(j - 1) + 1.0f;
                float y0f = floorf(ys), x0f = floorf(xs);
                float wy = ys - y0f, wx = xs - x0f;
                int iy0 = (int)y0f, ix0 = (int)x0f;
                float a = 0.0f;
#pragma unroll
                for (int dy = 0; dy < 2; ++dy) {
#pragma unroll
                    for (int dx = 0; dx < 2; ++dx) {
                        int iy = iy0 + dy, ix = ix0 + dx;
                        float wgt = (dy ? wy : 1.0f - wy) * (dx ? wx : 1.0f - wx);
                        bool valid = (iy >= 0) && (iy < 3) && (ix >= 0) && (ix < 3);
                        int iyc = min(max(iy, 0), 2), ixc = min(max(ix, 0), 2);
                        a += bb[h][iyc * 3 + ixc] * (valid ? wgt : 0.0f);
                    }
                }
                w45[h][i * 3 + j] = a;
            }
        }
    }

#pragma unroll
    for (int r = 0; r < NORI; ++r) {
        int rr = r & 3;
#pragma unroll
        for (int i = 0; i < 3; ++i) {
#pragma unroll
            for (int j = 0; j < 3; ++j) {
                int si, sj;
                if (rr == 0) { si = i;     sj = j;     }
                else if (rr == 1) { si = j;     sj = 2 - i; }
                else if (rr == 2) { si = 2 - i; sj = 2 - j; }
                else { si = 2 - j; sj = i;     }
                float v0 = (r < 4) ? bb[0][si * 3 + sj] : w45[0][si * 3 + sj];
                float v1 = (r < 4) ? bb[1][si * 3 + sj] : w45[1][si * 3 + sj];
                tw_h[(((r * 9) + (i * 3 + j)) * (CIN / 2) + cp) * COUT + o] =
                    packh2_rne(v0, v1);
            }
        }
    }
}

// Pack offset+mask conv weights as f16 channel-pairs:
// owm[(cp*27 + oc)*9 + t] = h2( w[oc][2cp][t], w[oc][2cp+1][t] ), oc<18 -> offw, else mskw
__global__ void pack_owm_kernel(const float* __restrict__ offw, const float* __restrict__ mskw,
                                unsigned int* __restrict__ owm) {
    int idx = blockIdx.x * blockDim.x + threadIdx.x;
    if (idx >= 27 * (CIN / 2)) return;
    int oc = idx % 27, cp = idx / 27;
    const float* src = (oc < 18) ? (offw + oc * CIN * 9) : (mskw + (oc - 18) * CIN * 9);
#pragma unroll
    for (int t = 0; t < 9; ++t)
        owm[(cp * 27 + oc) * 9 + t] = packh2_rne(src[(2 * cp) * 9 + t], src[(2 * cp + 1) * 9 + t]);
}

// K1: 3x3 conv 32ch -> 18 offset + 9 sigmoided mask channels, planar om[27][HW].
// f16 dot2; weights via wave-uniform s_load stream. (R10: ~40us, verified)
__global__ __launch_bounds__(256, 4) void offset_mask_kernel(
    const float* __restrict__ x,
    const unsigned int* __restrict__ owm,
    const float* __restrict__ offb, const float* __restrict__ mskb,
    float* __restrict__ om)
{
    __shared__ unsigned int Lp[8 * CHS1];   // 8 channel-pairs of f16x2 cells

    const int tiles_x = IMG / TS;
    int bid = (int)blockIdx.x;
    bid = (bid % 8) * (1024 / 8) + bid / 8;   // XCD band swizzle (bijective)
    int bx = bid % tiles_x, by = bid / tiles_x;
    int tx = threadIdx.x & 15, ty = threadIdx.x >> 4;
    int X = bx * TS + tx, Y = by * TS + ty;
    int p = Y * IMG + X;
    int y0w = by * TS - 1, x0w = bx * TS - 1;

    float acc[27];
#pragma unroll
    for (int i = 0; i < 18; ++i) acc[i] = offb[i];
#pragma unroll
    for (int i = 0; i < 9; ++i) acc[18 + i] = mskb[i];

    for (int pb = 0; pb < 2; ++pb) {          // pair-blocks: cp 0..7, 8..15
        __syncthreads();
        for (int i = threadIdx.x; i < 8 * (W1 * W1); i += 256) {
            int pr = i / (W1 * W1), cell = i % (W1 * W1);
            int rr = cell / W1, cc = cell % W1;
            int gy = y0w + rr, gx = x0w + cc;
            float a = 0.0f, b = 0.0f;
            if ((unsigned)gy < (unsigned)IMG && (unsigned)gx < (unsigned)IMG) {
                const float* x0 = x + ((pb * 8 + pr) * 2) * HW + gy * IMG + gx;
                a = x0[0]; b = x0[HW];
            }
            Lp[pr * CHS1 + rr * WR1 + cc] = packh2_rne(a, b);
        }
        __syncthreads();

        for (int pr = 0; pr < 8; ++pr) {
            int cp = pb * 8 + pr;
            int base = pr * CHS1 + ty * WR1 + tx;
            unsigned int v2[9];
#pragma unroll
            for (int j = 0; j < 3; ++j) {
                v2[j * 3 + 0] = Lp[base + j * WR1 + 0];
                v2[j * 3 + 1] = Lp[base + j * WR1 + 1];
                v2[j * 3 + 2] = Lp[base + j * WR1 + 2];
            }
            const unsigned int* wp = owm + cp * 27 * 9;   // wave-uniform -> s_load
#pragma unroll
            for (int oc = 0; oc < 27; ++oc)
#pragma unroll
                for (int t = 0; t < 9; ++t)
                    acc[oc] = dot2acc(v2[t], wp[oc * 9 + t], acc[oc]);
        }
    }

    acc[8] = 0.0f; acc[9] = 0.0f; acc[22] = 0.0f;
#pragma unroll
    for (int oc = 0; oc < 18; ++oc) om[oc * HW + p] = acc[oc];
#pragma unroll
    for (int mk = 0; mk < 9; ++mk)
        om[(18 + mk) * HW + p] = 1.0f / (1.0f + __expf(-acc[18 + mk]));
}

// K2: deformable sampling + per-pixel GEMV (f16 dot2, fp32 accum) + relu.
// R11 structure (single 32-ch f16-pair staging, pk_fma bilinear, one ds_read
// per corner pair) + R9's EXPLICIT runi branch: `runi ? rfl : r` killed the
// scalarization (per-lane select -> address not provably uniform -> 1152
// global_load_dwordx4 came back; R11 regressed 162->190us). The branch bodies
// must be duplicated so the uniform path's tw address is SGPR-derived s_load.
__global__ __launch_bounds__(256, 2) void deform_gemv_kernel(
    const float* __restrict__ x,
    const float* __restrict__ om,
    const float* __restrict__ gm,
    const unsigned int* __restrict__ tw_h,
    float* __restrict__ out)
{
    __shared__ unsigned int Lp[16 * CHS2];   // 16 pairs x 600 = 38400 B

    const int tiles_x = IMG / TS;
    int bid = (int)blockIdx.x;
    bid = (bid % 8) * (1024 / 8) + bid / 8;
    int bx = bid % tiles_x, by = bid / tiles_x;
    int tx = threadIdx.x & 15, ty = threadIdx.x >> 4;
    int X = bx * TS + tx, Y = by * TS + ty;
    int p = Y * IMG + X;
    int y0w = by * TS - HALO, x0w = bx * TS - HALO;

    int r = 0;
#pragma unroll
    for (int n = 1; n < NORI; ++n) r = (gm[n * HW + p] > 0.5f) ? n : r;
    int rfl = __builtin_amdgcn_readfirstlane(r);
    bool runi = __all(r == rfl);

    float oacc[32];
#pragma unroll
    for (int o = 0; o < 32; ++o) oacc[o] = 0.0f;

    // stage all 32 channels as f16 pairs (RNE)
    for (int i = threadIdx.x; i < 16 * (WIN * WIN); i += 256) {
        int pr = i / (WIN * WIN), cell = i % (WIN * WIN);
        int rr = cell / WIN, cc = cell % WIN;
        int gy = y0w + rr, gx = x0w + cc;
        float a = 0.0f, b = 0.0f;
        if ((unsigned)gy < (unsigned)IMG && (unsigned)gx < (unsigned)IMG) {
            const float* x0 = x + (2 * pr) * HW + gy * IMG + gx;
            a = x0[0]; b = x0[HW];
        }
        Lp[pr * CHS2 + rr * WROW + cc] = packh2_rne(a, b);
    }
    __syncthreads();

    for (int k = 0; k < 9; ++k) {   // runtime loop: small body, no arrays
        int ky = k / 3, kx = k - ky * 3;
        float offy = om[(2 * k) * HW + p];
        float offx = om[(2 * k + 1) * HW + p];
        float m    = om[(18 + k) * HW + p];
        float pyf = (float)(Y - 1 + ky) + offy;
        float pxf = (float)(X - 1 + kx) + offx;
        float y0f = floorf(pyf), x0f = floorf(pxf);
        float wy = pyf - y0f, wx = pxf - x0f;
        int iy0 = (int)y0f, ix0 = (int)x0f;
        int iy1 = iy0 + 1, ix1 = ix0 + 1;
        float vy0 = ((unsigned)iy0 < (unsigned)IMG) ? 1.0f : 0.0f;
        float vy1 = ((unsigned)iy1 < (unsigned)IMG) ? 1.0f : 0.0f;
        float vx0 = ((unsigned)ix0 < (unsigned)IMG) ? 1.0f : 0.0f;
        float vx1 = ((unsigned)ix1 < (unsigned)IMG) ? 1.0f : 0.0f;
        float w00 = m * (1.0f - wy) * (1.0f - wx) * vy0 * vx0;
        float w01 = m * (1.0f - wy) * wx * vy0 * vx1;
        float w10 = m * wy * (1.0f - wx) * vy1 * vx0;
        float w11 = m * wy * wx * vy1 * vx1;

        // unclamped window coords: whole 2x2 quad in window -> zero-padded
        // LDS + weight-0 OOB corners make static-offset reads exact.
        int ryu = iy0 - y0w, rxu = ix0 - x0w;
        bool fast = ((unsigned)ryu < (WIN - 1)) && ((unsigned)rxu < (WIN - 1));
        int lq = ryu * WROW + rxu;

        if (__all(fast)) {
            h2 w00h = splat2(w00), w01h = splat2(w01);
            h2 w10h = splat2(w10), w11h = splat2(w11);
            if (runi) {
                // rfl is SGPR -> tp is wave-uniform -> tw via s_load stream
                const uint4* tp = (const uint4*)(tw_h + (unsigned)((rfl * 9 + k) * (CIN / 2)) * COUT);
                for (int cp = 0; cp < CIN / 2; ++cp) {
                    int lb = cp * CHS2 + lq;
                    h2 v00 = __builtin_bit_cast(h2, Lp[lb]);
                    h2 v01 = __builtin_bit_cast(h2, Lp[lb + 1]);
                    h2 v10 = __builtin_bit_cast(h2, Lp[lb + WROW]);
                    h2 v11 = __builtin_bit_cast(h2, Lp[lb + WROW + 1]);
                    h2 s = w00h * v00 + w01h * v01 + w10h * v10 + w11h * v11;
                    unsigned int s2 = __builtin_bit_cast(unsigned int, s);
                    GEMV8(tp + cp * 8, s2);
                }
            } else {
                const uint4* tp = (const uint4*)(tw_h + (unsigned)((r * 9 + k) * (CIN / 2)) * COUT);
                for (int cp = 0; cp < CIN / 2; ++cp) {
                    int lb = cp * CHS2 + lq;
                    h2 v00 = __builtin_bit_cast(h2, Lp[lb]);
                    h2 v01 = __builtin_bit_cast(h2, Lp[lb + 1]);
                    h2 v10 = __builtin_bit_cast(h2, Lp[lb + WROW]);
                    h2 v11 = __builtin_bit_cast(h2, Lp[lb + WROW + 1]);
                    h2 s = w00h * v00 + w01h * v01 + w10h * v10 + w11h * v11;
                    unsigned int s2 = __builtin_bit_cast(unsigned int, s);
                    GEMV8(tp + cp * 8, s2);
                }
            }
        } else {
            // slow path (rare, |offset| >= ~3): exact f32 global reads, clamped
            int cy0 = min(max(iy0, 0), IMG - 1), cy1 = min(max(iy1, 0), IMG - 1);
            int cx0 = min(max(ix0, 0), IMG - 1), cx1 = min(max(ix1, 0), IMG - 1);
            int g00 = cy0 * IMG + cx0, g01 = cy0 * IMG + cx1;
            int g10 = cy1 * IMG + cx0, g11 = cy1 * IMG + cx1;
            const uint4* tp = (const uint4*)(tw_h + (unsigned)((r * 9 + k) * (CIN / 2)) * COUT);
            for (int cp = 0; cp < CIN / 2; ++cp) {
                const float* xc0 = x + (2 * cp) * HW;
                const float* xc1 = xc0 + HW;
                float s0 = fmaf(w00, xc0[g00], fmaf(w01, xc0[g01],
                           fmaf(w10, xc0[g10], w11 * xc0[g11])));
                float s1 = fmaf(w00, xc1[g00], fmaf(w01, xc1[g01],
                           fmaf(w10, xc1[g10], w11 * xc1[g11])));
                unsigned int s2 = packh2(s0, s1);
                GEMV8(tp + cp * 8, s2);
            }
        }
    }

#pragma unroll
    for (int o = 0; o < 32; ++o) out[o * HW + p] = fmaxf(oacc[o], 0.0f);
}

extern "C" void kernel_launch(void* const* d_in, const int* in_sizes, int n_in,
                              void* d_out, int out_size, void* d_ws, size_t ws_size,
                              hipStream_t stream) {
    const float* x      = (const float*)d_in[0];
    const float* weight = (const float*)d_in[1];
    const float* offw   = (const float*)d_in[2];
    const float* offb   = (const float*)d_in[3];
    const float* mskw   = (const float*)d_in[4];
    const float* mskb   = (const float*)d_in[5];
    const float* gm     = (const float*)d_in[6];
    float* out = (float*)d_out;

    unsigned int* tw_h = (unsigned int*)d_ws;                   // 147456 B
    unsigned int* owm  = (unsigned int*)((char*)d_ws + 147456); // 15552 B
    float* om = (float*)((char*)d_ws + 294912);                 // 27*HW*4 = 28.3 MB

    build_tw_kernel<<<2, 256, 0, stream>>>(weight, tw_h);
    pack_owm_kernel<<<2, 256, 0, stream>>>(offw, mskw, owm);

    const int tiles = (IMG / TS) * (IMG / TS); // 1024
    offset_mask_kernel<<<tiles, 256, 0, stream>>>(x, owm, offb, mskb, om);
    deform_gemv_kernel<<<tiles, 256, 0, stream>>>(x, om, gm, tw_h, out);
}

// Round 13
// 207.247 us; speedup vs baseline: 1.1244x; 1.1244x over previous
//
#include <hip/hip_runtime.h>

#define IMG 512
#define CIN 32
#define COUT 32
#define NORI 8
#define HW (IMG*IMG)

#define TS 16

// ---- K1 staging geometry (halo 1), f16 channel-pair cells ----
#define W1 18
#define WR1 19
#define CHS1 (W1*WR1)      // 342 uints per channel-pair
// ---- K2 staging geometry (halo 4), f16 channel-pair cells ----
#define HALO 4
#define WIN 24
#define WROW 25
#define CHS2 (WIN*WROW)    // 600 uints per channel-pair

typedef _Float16 h2 __attribute__((ext_vector_type(2)));
typedef __fp16  fp16v2 __attribute__((ext_vector_type(2)));

__device__ __forceinline__ float dot2acc(unsigned int a, unsigned int b, float c) {
#if __has_builtin(__builtin_amdgcn_fdot2)
    return __builtin_amdgcn_fdot2(__builtin_bit_cast(h2, a),
                                  __builtin_bit_cast(h2, b), c, false);
#else
    h2 av = __builtin_bit_cast(h2, a), bv = __builtin_bit_cast(h2, b);
    return fmaf((float)av[0], (float)bv[0], fmaf((float)av[1], (float)bv[1], c));
#endif
}

__device__ __forceinline__ unsigned int packh2(float a, float b) {
#if __has_builtin(__builtin_amdgcn_cvt_pkrtz)
    fp16v2 r = __builtin_amdgcn_cvt_pkrtz(a, b);
    return __builtin_bit_cast(unsigned int, r);
#else
    h2 r; r[0] = (_Float16)a; r[1] = (_Float16)b;
    return __builtin_bit_cast(unsigned int, r);
#endif
}

__device__ __forceinline__ unsigned int packh2_rne(float a, float b) {
    h2 r; r[0] = (_Float16)a; r[1] = (_Float16)b;   // RNE casts
    return __builtin_bit_cast(unsigned int, r);
}

__device__ __forceinline__ h2 splat2(float a) {
    _Float16 h = (_Float16)a;
    h2 r; r[0] = h; r[1] = h;
    return r;
}

#define GEMV8(TP, S2) do {                                             \
    const uint4* _tp = (TP);                                           \
    _Pragma("unroll")                                                  \
    for (int q = 0; q < 8; ++q) {                                      \
        uint4 u = _tp[q];                                              \
        oacc[q * 4 + 0] = dot2acc((S2), u.x, oacc[q * 4 + 0]);         \
        oacc[q * 4 + 1] = dot2acc((S2), u.y, oacc[q * 4 + 1]);         \
        oacc[q * 4 + 2] = dot2acc((S2), u.z, oacc[q * 4 + 2]);         \
        oacc[q * 4 + 3] = dot2acc((S2), u.w, oacc[q * 4 + 3]);         \
    }                                                                  \
} while (0)

// tw_h layout (uint = h2 = channel pair): tw_h[((r*9 + k)*(CIN/2) + cp)*COUT + o]
__global__ void build_tw_kernel(const float* __restrict__ weight, unsigned int* __restrict__ tw_h) {
    int idx = blockIdx.x * blockDim.x + threadIdx.x; // 0..511
    if (idx >= COUT * (CIN / 2)) return;
    int o = idx & 31, cp = idx >> 5;

    float bb[2][9], w45[2][9];
    const float cs = 0.70710678f;
#pragma unroll
    for (int h = 0; h < 2; ++h) {
        int c = 2 * cp + h;
#pragma unroll
        for (int t = 0; t < 9; ++t) bb[h][t] = weight[(o * CIN + c) * 9 + t];
#pragma unroll
        for (int i = 0; i < 3; ++i) {
#pragma unroll
            for (int j = 0; j < 3; ++j) {
                float ys = cs * (float)(i - 1) + cs * (float)(j - 1) + 1.0f;
                float xs = -cs * (float)(i - 1) + cs * (float)(j - 1) + 1.0f;
                float y0f = floorf(ys), x0f = floorf(xs);
                float wy = ys - y0f, wx = xs - x0f;
                int iy0 = (int)y0f, ix0 = (int)x0f;
                float a = 0.0f;
#pragma unroll
                for (int dy = 0; dy < 2; ++dy) {
#pragma unroll
                    for (int dx = 0; dx < 2; ++dx) {
                        int iy = iy0 + dy, ix = ix0 + dx;
                        float wgt = (dy ? wy : 1.0f - wy) * (dx ? wx : 1.0f - wx);
                        bool valid = (iy >= 0) && (iy < 3) && (ix >= 0) && (ix < 3);
                        int iyc = min(max(iy, 0), 2), ixc = min(max(ix, 0), 2);
                        a += bb[h][iyc * 3 + ixc] * (valid ? wgt : 0.0f);
                    }
                }
                w45[h][i * 3 + j] = a;
            }
        }
    }

#pragma unroll
    for (int r = 0; r < NORI; ++r) {
        int rr = r & 3;
#pragma unroll
        for (int i = 0; i < 3; ++i) {
#pragma unroll
            for (int j = 0; j < 3; ++j) {
                int si, sj;
                if (rr == 0) { si = i;     sj = j;     }
                else if (rr == 1) { si = j;     sj = 2 - i; }
                else if (rr == 2) { si = 2 - i; sj = 2 - j; }
                else { si = 2 - j; sj = i;     }
                float v0 = (r < 4) ? bb[0][si * 3 + sj] : w45[0][si * 3 + sj];
                float v1 = (r < 4) ? bb[1][si * 3 + sj] : w45[1][si * 3 + sj];
                tw_h[(((r * 9) + (i * 3 + j)) * (CIN / 2) + cp) * COUT + o] =
                    packh2_rne(v0, v1);
            }
        }
    }
}

// Pack offset+mask conv weights as f16 channel-pairs:
// owm[(cp*27 + oc)*9 + t] = h2( w[oc][2cp][t], w[oc][2cp+1][t] ), oc<18 -> offw, else mskw
__global__ void pack_owm_kernel(const float* __restrict__ offw, const float* __restrict__ mskw,
                                unsigned int* __restrict__ owm) {
    int idx = blockIdx.x * blockDim.x + threadIdx.x;
    if (idx >= 27 * (CIN / 2)) return;
    int oc = idx % 27, cp = idx / 27;
    const float* src = (oc < 18) ? (offw + oc * CIN * 9) : (mskw + (oc - 18) * CIN * 9);
#pragma unroll
    for (int t = 0; t < 9; ++t)
        owm[(cp * 27 + oc) * 9 + t] = packh2_rne(src[(2 * cp) * 9 + t], src[(2 * cp + 1) * 9 + t]);
}

// K1: 3x3 conv 32ch -> 18 offset + 9 sigmoided mask channels, planar om[27][HW].
// f16 dot2; weights via wave-uniform s_load stream. (R10: ~40us, verified)
__global__ __launch_bounds__(256, 4) void offset_mask_kernel(
    const float* __restrict__ x,
    const unsigned int* __restrict__ owm,
    const float* __restrict__ offb, const float* __restrict__ mskb,
    float* __restrict__ om)
{
    __shared__ unsigned int Lp[8 * CHS1];   // 8 channel-pairs of f16x2 cells

    const int tiles_x = IMG / TS;
    int bid = (int)blockIdx.x;
    bid = (bid % 8) * (1024 / 8) + bid / 8;   // XCD band swizzle (bijective)
    int bx = bid % tiles_x, by = bid / tiles_x;
    int tx = threadIdx.x & 15, ty = threadIdx.x >> 4;
    int X = bx * TS + tx, Y = by * TS + ty;
    int p = Y * IMG + X;
    int y0w = by * TS - 1, x0w = bx * TS - 1;

    float acc[27];
#pragma unroll
    for (int i = 0; i < 18; ++i) acc[i] = offb[i];
#pragma unroll
    for (int i = 0; i < 9; ++i) acc[18 + i] = mskb[i];

    for (int pb = 0; pb < 2; ++pb) {          // pair-blocks: cp 0..7, 8..15
        __syncthreads();
        for (int i = threadIdx.x; i < 8 * (W1 * W1); i += 256) {
            int pr = i / (W1 * W1), cell = i % (W1 * W1);
            int rr = cell / W1, cc = cell % W1;
            int gy = y0w + rr, gx = x0w + cc;
            float a = 0.0f, b = 0.0f;
            if ((unsigned)gy < (unsigned)IMG && (unsigned)gx < (unsigned)IMG) {
                const float* x0 = x + ((pb * 8 + pr) * 2) * HW + gy * IMG + gx;
                a = x0[0]; b = x0[HW];
            }
            Lp[pr * CHS1 + rr * WR1 + cc] = packh2_rne(a, b);
        }
        __syncthreads();

        for (int pr = 0; pr < 8; ++pr) {
            int cp = pb * 8 + pr;
            int base = pr * CHS1 + ty * WR1 + tx;
            unsigned int v2[9];
#pragma unroll
            for (int j = 0; j < 3; ++j) {
                v2[j * 3 + 0] = Lp[base + j * WR1 + 0];
                v2[j * 3 + 1] = Lp[base + j * WR1 + 1];
                v2[j * 3 + 2] = Lp[base + j * WR1 + 2];
            }
            const unsigned int* wp = owm + cp * 27 * 9;   // wave-uniform -> s_load
#pragma unroll
            for (int oc = 0; oc < 27; ++oc)
#pragma unroll
                for (int t = 0; t < 9; ++t)
                    acc[oc] = dot2acc(v2[t], wp[oc * 9 + t], acc[oc]);
        }
    }

    acc[8] = 0.0f; acc[9] = 0.0f; acc[22] = 0.0f;
#pragma unroll
    for (int oc = 0; oc < 18; ++oc) om[oc * HW + p] = acc[oc];
#pragma unroll
    for (int mk = 0; mk < 9; ++mk)
        om[(18 + mk) * HW + p] = 1.0f / (1.0f + __expf(-acc[18 + mk]));
}

// K2: deformable sampling + per-pixel GEMV (f16 dot2, fp32 accum) + relu.
// R13: back to R10's cb-blocked structure (2 pair-blocks x 8 pairs, 19.2KB LDS)
// + batched corner ds_reads into registers per k (vq[8][4], statically indexed)
// so ALL ds_reads drain with ONE lgkmcnt before the s_load-weight GEMV stream
// (SMEM and DS share lgkmcnt; interleaving them serialized R11/R12).
__global__ __launch_bounds__(256, 2) void deform_gemv_kernel(
    const float* __restrict__ x,
    const float* __restrict__ om,
    const float* __restrict__ gm,
    const unsigned int* __restrict__ tw_h,
    float* __restrict__ out)
{
    __shared__ unsigned int Lp[8 * CHS2];   // 8 pairs x 600 x 4B = 19200 B

    const int tiles_x = IMG / TS;
    int bid = (int)blockIdx.x;
    bid = (bid % 8) * (1024 / 8) + bid / 8;
    int bx = bid % tiles_x, by = bid / tiles_x;
    int tx = threadIdx.x & 15, ty = threadIdx.x >> 4;
    int X = bx * TS + tx, Y = by * TS + ty;
    int p = Y * IMG + X;
    int y0w = by * TS - HALO, x0w = bx * TS - HALO;

    int r = 0;
#pragma unroll
    for (int n = 1; n < NORI; ++n) r = (gm[n * HW + p] > 0.5f) ? n : r;
    int rfl = __builtin_amdgcn_readfirstlane(r);
    bool runi = __all(r == rfl);

    float oacc[32];
#pragma unroll
    for (int o = 0; o < 32; ++o) oacc[o] = 0.0f;

    for (int pb = 0; pb < 2; ++pb) {          // pair-blocks: pairs 0..7, 8..15
        __syncthreads();
        for (int i = threadIdx.x; i < 8 * (WIN * WIN); i += 256) {
            int pr = i / (WIN * WIN), cell = i % (WIN * WIN);
            int rr = cell / WIN, cc = cell % WIN;
            int gy = y0w + rr, gx = x0w + cc;
            float a = 0.0f, b = 0.0f;
            if ((unsigned)gy < (unsigned)IMG && (unsigned)gx < (unsigned)IMG) {
                const float* x0 = x + (pb * 16 + 2 * pr) * HW + gy * IMG + gx;
                a = x0[0]; b = x0[HW];
            }
            Lp[pr * CHS2 + rr * WROW + cc] = packh2_rne(a, b);
        }
        __syncthreads();

        for (int k = 0; k < 9; ++k) {   // runtime loop: small body
            int ky = k / 3, kx = k - ky * 3;
            float offy = om[(2 * k) * HW + p];
            float offx = om[(2 * k + 1) * HW + p];
            float m    = om[(18 + k) * HW + p];
            float pyf = (float)(Y - 1 + ky) + offy;
            float pxf = (float)(X - 1 + kx) + offx;
            float y0f = floorf(pyf), x0f = floorf(pxf);
            float wy = pyf - y0f, wx = pxf - x0f;
            int iy0 = (int)y0f, ix0 = (int)x0f;
            int iy1 = iy0 + 1, ix1 = ix0 + 1;
            float vy0 = ((unsigned)iy0 < (unsigned)IMG) ? 1.0f : 0.0f;
            float vy1 = ((unsigned)iy1 < (unsigned)IMG) ? 1.0f : 0.0f;
            float vx0 = ((unsigned)ix0 < (unsigned)IMG) ? 1.0f : 0.0f;
            float vx1 = ((unsigned)ix1 < (unsigned)IMG) ? 1.0f : 0.0f;
            float w00 = m * (1.0f - wy) * (1.0f - wx) * vy0 * vx0;
            float w01 = m * (1.0f - wy) * wx * vy0 * vx1;
            float w10 = m * wy * (1.0f - wx) * vy1 * vx0;
            float w11 = m * wy * wx * vy1 * vx1;

            // unclamped window coords: whole 2x2 quad in window -> zero-padded
            // LDS + weight-0 OOB corners make static-offset reads exact.
            int ryu = iy0 - y0w, rxu = ix0 - x0w;
            bool fast = ((unsigned)ryu < (WIN - 1)) && ((unsigned)rxu < (WIN - 1));
            int lq = ryu * WROW + rxu;

            if (__all(fast)) {
                // batch ALL corner reads -> registers, single lgkm drain
                unsigned int vq[8][4];
#pragma unroll
                for (int cp = 0; cp < 8; ++cp) {
                    int lb = cp * CHS2 + lq;
                    vq[cp][0] = Lp[lb];        vq[cp][1] = Lp[lb + 1];
                    vq[cp][2] = Lp[lb + WROW]; vq[cp][3] = Lp[lb + WROW + 1];
                }
                h2 w00h = splat2(w00), w01h = splat2(w01);
                h2 w10h = splat2(w10), w11h = splat2(w11);
                if (runi) {
                    // rfl is SGPR -> wave-uniform tw address -> s_load stream
                    const uint4* tp = (const uint4*)(tw_h +
                        (unsigned)((rfl * 9 + k) * (CIN / 2) + pb * 8) * COUT);
#pragma unroll
                    for (int cp = 0; cp < 8; ++cp) {
                        h2 s = w00h * __builtin_bit_cast(h2, vq[cp][0])
                             + w01h * __builtin_bit_cast(h2, vq[cp][1])
                             + w10h * __builtin_bit_cast(h2, vq[cp][2])
                             + w11h * __builtin_bit_cast(h2, vq[cp][3]);
                        unsigned int s2 = __builtin_bit_cast(unsigned int, s);
                        GEMV8(tp + cp * 8, s2);
                    }
                } else {
                    const uint4* tp = (const uint4*)(tw_h +
                        (unsigned)((r * 9 + k) * (CIN / 2) + pb * 8) * COUT);
#pragma unroll
                    for (int cp = 0; cp < 8; ++cp) {
                        h2 s = w00h * __builtin_bit_cast(h2, vq[cp][0])
                             + w01h * __builtin_bit_cast(h2, vq[cp][1])
                             + w10h * __builtin_bit_cast(h2, vq[cp][2])
                             + w11h * __builtin_bit_cast(h2, vq[cp][3]);
                        unsigned int s2 = __builtin_bit_cast(unsigned int, s);
                        GEMV8(tp + cp * 8, s2);
                    }
                }
            } else {
                // slow path (rare, |offset| >= ~3): exact f32 global reads, clamped
                int cy0 = min(max(iy0, 0), IMG - 1), cy1 = min(max(iy1, 0), IMG - 1);
                int cx0 = min(max(ix0, 0), IMG - 1), cx1 = min(max(ix1, 0), IMG - 1);
                int g00 = cy0 * IMG + cx0, g01 = cy0 * IMG + cx1;
                int g10 = cy1 * IMG + cx0, g11 = cy1 * IMG + cx1;
                const uint4* tp = (const uint4*)(tw_h +
                    (unsigned)((r * 9 + k) * (CIN / 2) + pb * 8) * COUT);
                for (int cp = 0; cp < 8; ++cp) {
                    const float* xc0 = x + (pb * 16 + 2 * cp) * HW;
                    const float* xc1 = xc0 + HW;
                    float s0 = fmaf(w00, xc0[g00], fmaf(w01, xc0[g01],
                               fmaf(w10, xc0[g10], w11 * xc0[g11])));
                    float s1 = fmaf(w00, xc1[g00], fmaf(w01, xc1[g01],
                               fmaf(w10, xc1[g10], w11 * xc1[g11])));
                    unsigned int s2 = packh2(s0, s1);
                    GEMV8(tp + cp * 8, s2);
                }
            }
        }
    }

#pragma unroll
    for (int o = 0; o < 32; ++o) out[o * HW + p] = fmaxf(oacc[o], 0.0f);
}

extern "C" void kernel_launch(void* const* d_in, const int* in_sizes, int n_in,
                              void* d_out, int out_size, void* d_ws, size_t ws_size,
                              hipStream_t stream) {
    const float* x      = (const float*)d_in[0];
    const float* weight = (const float*)d_in[1];
    const float* offw   = (const float*)d_in[2];
    const float* offb   = (const float*)d_in[3];
    const float* mskw   = (const float*)d_in[4];
    const float* mskb   = (const float*)d_in[5];
    const float* gm     = (const float*)d_in[6];
    float* out = (float*)d_out;

    unsigned int* tw_h = (unsigned int*)d_ws;                   // 147456 B
    unsigned int* owm  = (unsigned int*)((char*)d_ws + 147456); // 15552 B
    float* om = (float*)((char*)d_ws + 294912);                 // 27*HW*4 = 28.3 MB

    build_tw_kernel<<<2, 256, 0, stream>>>(weight, tw_h);
    pack_owm_kernel<<<2, 256, 0, stream>>>(offw, mskw, owm);

    const int tiles = (IMG / TS) * (IMG / TS); // 1024
    offset_mask_kernel<<<tiles, 256, 0, stream>>>(x, owm, offb, mskb, om);
    deform_gemv_kernel<<<tiles, 256, 0, stream>>>(x, om, gm, tw_h, out);
}

// Round 14
// 135.593 us; speedup vs baseline: 1.7187x; 1.5284x over previous
//
#include <hip/hip_runtime.h>

#define IMG 512
#define CIN 32
#define COUT 32
#define NORI 8
#define HW (IMG*IMG)

#define TS 16

// ---- K1 staging geometry (halo 1), f16 channel-pair cells ----
#define W1 18
#define WR1 19
#define CHS1 (W1*WR1)
// ---- K2 staging geometry (halo 4), f16 channel-pair cells ----
#define HALO 4
#define WIN 24
#define WROW 25
#define CHS2 (WIN*WROW)    // 600 uints per channel-pair plane

typedef _Float16 h2 __attribute__((ext_vector_type(2)));
typedef __fp16  fp16v2 __attribute__((ext_vector_type(2)));
typedef _Float16 f16x8 __attribute__((ext_vector_type(8)));   // CK-style MFMA operand
typedef float    f32x4 __attribute__((ext_vector_type(4)));

__device__ __forceinline__ float dot2acc(unsigned int a, unsigned int b, float c) {
#if __has_builtin(__builtin_amdgcn_fdot2)
    return __builtin_amdgcn_fdot2(__builtin_bit_cast(h2, a),
                                  __builtin_bit_cast(h2, b), c, false);
#else
    h2 av = __builtin_bit_cast(h2, a), bv = __builtin_bit_cast(h2, b);
    return fmaf((float)av[0], (float)bv[0], fmaf((float)av[1], (float)bv[1], c));
#endif
}

__device__ __forceinline__ unsigned int packh2(float a, float b) {
#if __has_builtin(__builtin_amdgcn_cvt_pkrtz)
    fp16v2 r = __builtin_amdgcn_cvt_pkrtz(a, b);
    return __builtin_bit_cast(unsigned int, r);
#else
    h2 r; r[0] = (_Float16)a; r[1] = (_Float16)b;
    return __builtin_bit_cast(unsigned int, r);
#endif
}

__device__ __forceinline__ unsigned int packh2_rne(float a, float b) {
    h2 r; r[0] = (_Float16)a; r[1] = (_Float16)b;   // RNE casts
    return __builtin_bit_cast(unsigned int, r);
}

#define GEMV8(TP, S2) do {                                             \
    const uint4* _tp = (TP);                                           \
    _Pragma("unroll")                                                  \
    for (int q = 0; q < 8; ++q) {                                      \
        uint4 u = _tp[q];                                              \
        oacc[q * 4 + 0] = dot2acc((S2), u.x, oacc[q * 4 + 0]);         \
        oacc[q * 4 + 1] = dot2acc((S2), u.y, oacc[q * 4 + 1]);         \
        oacc[q * 4 + 2] = dot2acc((S2), u.z, oacc[q * 4 + 2]);         \
        oacc[q * 4 + 3] = dot2acc((S2), u.w, oacc[q * 4 + 3]);         \
    }                                                                  \
} while (0)

// tw_h layout (uint = h2 = channel pair): tw_h[((r*9 + k)*(CIN/2) + cp)*COUT + o]
__global__ void build_tw_kernel(const float* __restrict__ weight, unsigned int* __restrict__ tw_h) {
    int idx = blockIdx.x * blockDim.x + threadIdx.x; // 0..511
    if (idx >= COUT * (CIN / 2)) return;
    int o = idx & 31, cp = idx >> 5;

    float bb[2][9], w45[2][9];
    const float cs = 0.70710678f;
#pragma unroll
    for (int h = 0; h < 2; ++h) {
        int c = 2 * cp + h;
#pragma unroll
        for (int t = 0; t < 9; ++t) bb[h][t] = weight[(o * CIN + c) * 9 + t];
#pragma unroll
        for (int i = 0; i < 3; ++i) {
#pragma unroll
            for (int j = 0; j < 3; ++j) {
                float ys = cs * (float)(i - 1) + cs * (float)(j - 1) + 1.0f;
                float xs = -cs * (float)(i - 1) + cs * (float)(j - 1) + 1.0f;
                float y0f = floorf(ys), x0f = floorf(xs);
                float wy = ys - y0f, wx = xs - x0f;
                int iy0 = (int)y0f, ix0 = (int)x0f;
                float a = 0.0f;
#pragma unroll
                for (int dy = 0; dy < 2; ++dy) {
#pragma unroll
                    for (int dx = 0; dx < 2; ++dx) {
                        int iy = iy0 + dy, ix = ix0 + dx;
                        float wgt = (dy ? wy : 1.0f - wy) * (dx ? wx : 1.0f - wx);
                        bool valid = (iy >= 0) && (iy < 3) && (ix >= 0) && (ix < 3);
                        int iyc = min(max(iy, 0), 2), ixc = min(max(ix, 0), 2);
                        a += bb[h][iyc * 3 + ixc] * (valid ? wgt : 0.0f);
                    }
                }
                w45[h][i * 3 + j] = a;
            }
        }
    }

#pragma unroll
    for (int r = 0; r < NORI; ++r) {
        int rr = r & 3;
#pragma unroll
        for (int i = 0; i < 3; ++i) {
#pragma unroll
            for (int j = 0; j < 3; ++j) {
                int si, sj;
                if (rr == 0) { si = i;     sj = j;     }
                else if (rr == 1) { si = j;     sj = 2 - i; }
                else if (rr == 2) { si = 2 - i; sj = 2 - j; }
                else { si = 2 - j; sj = i;     }
                float v0 = (r < 4) ? bb[0][si * 3 + sj] : w45[0][si * 3 + sj];
                float v1 = (r < 4) ? bb[1][si * 3 + sj] : w45[1][si * 3 + sj];
                tw_h[(((r * 9) + (i * 3 + j)) * (CIN / 2) + cp) * COUT + o] =
                    packh2_rne(v0, v1);
            }
        }
    }
}

// Pack offset+mask conv weights as f16 channel-pairs
__global__ void pack_owm_kernel(const float* __restrict__ offw, const float* __restrict__ mskw,
                                unsigned int* __restrict__ owm) {
    int idx = blockIdx.x * blockDim.x + threadIdx.x;
    if (idx >= 27 * (CIN / 2)) return;
    int oc = idx % 27, cp = idx / 27;
    const float* src = (oc < 18) ? (offw + oc * CIN * 9) : (mskw + (oc - 18) * CIN * 9);
#pragma unroll
    for (int t = 0; t < 9; ++t)
        owm[(cp * 27 + oc) * 9 + t] = packh2_rne(src[(2 * cp) * 9 + t], src[(2 * cp + 1) * 9 + t]);
}

// K1: unchanged from R13 (verified ~40us)
__global__ __launch_bounds__(256, 4) void offset_mask_kernel(
    const float* __restrict__ x,
    const unsigned int* __restrict__ owm,
    const float* __restrict__ offb, const float* __restrict__ mskb,
    float* __restrict__ om)
{
    __shared__ unsigned int Lp[8 * CHS1];

    const int tiles_x = IMG / TS;
    int bid = (int)blockIdx.x;
    bid = (bid % 8) * (1024 / 8) + bid / 8;
    int bx = bid % tiles_x, by = bid / tiles_x;
    int tx = threadIdx.x & 15, ty = threadIdx.x >> 4;
    int X = bx * TS + tx, Y = by * TS + ty;
    int p = Y * IMG + X;
    int y0w = by * TS - 1, x0w = bx * TS - 1;

    float acc[27];
#pragma unroll
    for (int i = 0; i < 18; ++i) acc[i] = offb[i];
#pragma unroll
    for (int i = 0; i < 9; ++i) acc[18 + i] = mskb[i];

    for (int pb = 0; pb < 2; ++pb) {
        __syncthreads();
        for (int i = threadIdx.x; i < 8 * (W1 * W1); i += 256) {
            int pr = i / (W1 * W1), cell = i % (W1 * W1);
            int rr = cell / W1, cc = cell % W1;
            int gy = y0w + rr, gx = x0w + cc;
            float a = 0.0f, b = 0.0f;
            if ((unsigned)gy < (unsigned)IMG && (unsigned)gx < (unsigned)IMG) {
                const float* x0 = x + ((pb * 8 + pr) * 2) * HW + gy * IMG + gx;
                a = x0[0]; b = x0[HW];
            }
            Lp[pr * CHS1 + rr * WR1 + cc] = packh2_rne(a, b);
        }
        __syncthreads();

        for (int pr = 0; pr < 8; ++pr) {
            int cp = pb * 8 + pr;
            int base = pr * CHS1 + ty * WR1 + tx;
            unsigned int v2[9];
#pragma unroll
            for (int j = 0; j < 3; ++j) {
                v2[j * 3 + 0] = Lp[base + j * WR1 + 0];
                v2[j * 3 + 1] = Lp[base + j * WR1 + 1];
                v2[j * 3 + 2] = Lp[base + j * WR1 + 2];
            }
            const unsigned int* wp = owm + cp * 27 * 9;   // wave-uniform -> s_load
#pragma unroll
            for (int oc = 0; oc < 27; ++oc)
#pragma unroll
                for (int t = 0; t < 9; ++t)
                    acc[oc] = dot2acc(v2[t], wp[oc * 9 + t], acc[oc]);
        }
    }

    acc[8] = 0.0f; acc[9] = 0.0f; acc[22] = 0.0f;
#pragma unroll
    for (int oc = 0; oc < 18; ++oc) om[oc * HW + p] = acc[oc];
#pragma unroll
    for (int mk = 0; mk < 9; ++mk)
        om[(18 + mk) * HW + p] = 1.0f / (1.0f + __expf(-acc[18 + mk]));
}

// K2 (MFMA): per tile, out[256px,32o] = sum_k S_k[256px,32c] x TW[r][k][32c,32o]
// via mfma_f32_16x16x32_f16. Phase 1 precomputes per-(px,tap) bilinear weights
// (f16 pairs) + window index + sector into LDS; Phase 2: 4 waves x (4 Mtiles x
// 2 Ntiles) D-tiles, A assembled from LDS samples, B from L2-resident tw_h.
// Mixed-sector blocks: loop distinct r, masking A rows. Any out-of-window tap:
// whole-block exact-f32 fallback (offsets ~0.17 sigma -> essentially never).
__global__ __launch_bounds__(256, 2) void deform_mfma_kernel(
    const float* __restrict__ x,
    const float* __restrict__ om,
    const float* __restrict__ gm,
    const unsigned int* __restrict__ tw_h,
    float* __restrict__ out)
{
    __shared__ unsigned int Lx[16 * CHS2];      // 38400 B: 16 f16-pair planes
    __shared__ uint2 Wl[9 * 256];               // 18432 B: (w00,w01),(w10,w11) f16
    __shared__ unsigned short LQ[9 * 256];      // 4608 B: lq | r<<12
    __shared__ int flags[2];                    // [0]=rmask, [1]=anyslow

    const int tiles_x = IMG / TS;
    int bid = (int)blockIdx.x;
    bid = (bid % 8) * (1024 / 8) + bid / 8;
    int bx = bid % tiles_x, by = bid / tiles_x;
    int tid = threadIdx.x;
    int tx = tid & 15, ty = tid >> 4;
    int X = bx * TS + tx, Y = by * TS + ty;
    int p = Y * IMG + X;
    int y0w = by * TS - HALO, x0w = bx * TS - HALO;

    if (tid < 2) flags[tid] = 0;
    __syncthreads();

    // stage all 32 channels as f16 pairs (RNE)
    for (int i = tid; i < 16 * (WIN * WIN); i += 256) {
        int pr = i / (WIN * WIN), cell = i % (WIN * WIN);
        int rr = cell / WIN, cc = cell % WIN;
        int gy = y0w + rr, gx = x0w + cc;
        float a = 0.0f, b = 0.0f;
        if ((unsigned)gy < (unsigned)IMG && (unsigned)gx < (unsigned)IMG) {
            const float* x0 = x + (2 * pr) * HW + gy * IMG + gx;
            a = x0[0]; b = x0[HW];
        }
        Lx[pr * CHS2 + rr * WROW + cc] = packh2_rne(a, b);
    }

    int r = 0;
#pragma unroll
    for (int n = 1; n < NORI; ++n) r = (gm[n * HW + p] > 0.5f) ? n : r;

    // Phase 1: per-(pixel,tap) bilinear weights + window index -> LDS
    bool slow = false;
    for (int kt = 0; kt < 9; ++kt) {
        int ky = kt / 3, kx = kt - ky * 3;
        float offy = om[(2 * kt) * HW + p];
        float offx = om[(2 * kt + 1) * HW + p];
        float m    = om[(18 + kt) * HW + p];
        float pyf = (float)(Y - 1 + ky) + offy;
        float pxf = (float)(X - 1 + kx) + offx;
        float y0f = floorf(pyf), x0f = floorf(pxf);
        float wy = pyf - y0f, wx = pxf - x0f;
        int iy0 = (int)y0f, ix0 = (int)x0f;
        float vy0 = ((unsigned)iy0 < (unsigned)IMG) ? 1.0f : 0.0f;
        float vy1 = ((unsigned)(iy0 + 1) < (unsigned)IMG) ? 1.0f : 0.0f;
        float vx0 = ((unsigned)ix0 < (unsigned)IMG) ? 1.0f : 0.0f;
        float vx1 = ((unsigned)(ix0 + 1) < (unsigned)IMG) ? 1.0f : 0.0f;
        float w00 = m * (1.0f - wy) * (1.0f - wx) * vy0 * vx0;
        float w01 = m * (1.0f - wy) * wx * vy0 * vx1;
        float w10 = m * wy * (1.0f - wx) * vy1 * vx0;
        float w11 = m * wy * wx * vy1 * vx1;
        int ryu = iy0 - y0w, rxu = ix0 - x0w;
        bool fast = ((unsigned)ryu < (WIN - 1)) && ((unsigned)rxu < (WIN - 1));
        slow |= !fast;
        int lq = fast ? (ryu * WROW + rxu) : 0;
        Wl[kt * 256 + tid] = make_uint2(packh2_rne(w00, w01), packh2_rne(w10, w11));
        LQ[kt * 256 + tid] = (unsigned short)(lq | (r << 12));
    }
    atomicOr(&flags[0], 1 << r);
    if (slow) flags[1] = 1;   // same-value race OK
    __syncthreads();

    int rmaskv = flags[0];
    int anyslow = flags[1];

    if (anyslow) {
        // whole-block exact path (rare): per-thread f32, clamped global reads
        float oacc[32];
#pragma unroll
        for (int o = 0; o < 32; ++o) oacc[o] = 0.0f;
        for (int kt = 0; kt < 9; ++kt) {
            int ky = kt / 3, kx = kt - ky * 3;
            float offy = om[(2 * kt) * HW + p];
            float offx = om[(2 * kt + 1) * HW + p];
            float m    = om[(18 + kt) * HW + p];
            float pyf = (float)(Y - 1 + ky) + offy;
            float pxf = (float)(X - 1 + kx) + offx;
            float y0f = floorf(pyf), x0f = floorf(pxf);
            float wy = pyf - y0f, wx = pxf - x0f;
            int iy0 = (int)y0f, ix0 = (int)x0f;
            float vy0 = ((unsigned)iy0 < (unsigned)IMG) ? 1.0f : 0.0f;
            float vy1 = ((unsigned)(iy0 + 1) < (unsigned)IMG) ? 1.0f : 0.0f;
            float vx0 = ((unsigned)ix0 < (unsigned)IMG) ? 1.0f : 0.0f;
            float vx1 = ((unsigned)(ix0 + 1) < (unsigned)IMG) ? 1.0f : 0.0f;
            float w00 = m * (1.0f - wy) * (1.0f - wx) * vy0 * vx0;
            float w01 = m * (1.0f - wy) * wx * vy0 * vx1;
            float w10 = m * wy * (1.0f - wx) * vy1 * vx0;
            float w11 = m * wy * wx * vy1 * vx1;
            int cy0 = min(max(iy0, 0), IMG - 1), cy1 = min(max(iy0 + 1, 0), IMG - 1);
            int cx0 = min(max(ix0, 0), IMG - 1), cx1 = min(max(ix0 + 1, 0), IMG - 1);
            int g00 = cy0 * IMG + cx0, g01 = cy0 * IMG + cx1;
            int g10 = cy1 * IMG + cx0, g11 = cy1 * IMG + cx1;
            const uint4* tp = (const uint4*)(tw_h + (unsigned)((r * 9 + kt) * (CIN / 2)) * COUT);
            for (int cp = 0; cp < CIN / 2; ++cp) {
                const float* xc0 = x + (2 * cp) * HW;
                const float* xc1 = xc0 + HW;
                float s0 = fmaf(w00, xc0[g00], fmaf(w01, xc0[g01],
                           fmaf(w10, xc0[g10], w11 * xc0[g11])));
                float s1 = fmaf(w00, xc1[g00], fmaf(w01, xc1[g01],
                           fmaf(w10, xc1[g10], w11 * xc1[g11])));
                unsigned int s2 = packh2(s0, s1);
                GEMV8(tp + cp * 8, s2);
            }
        }
#pragma unroll
        for (int o = 0; o < 32; ++o) out[o * HW + p] = fmaxf(oacc[o], 0.0f);
        return;
    }

    // ---- MFMA path ----
    int lane = tid & 63, wid = tid >> 6;
    int lrow = lane & 15, lhi = lane >> 4;

    f32x4 acc[4][2] = {};

    int rm = __builtin_amdgcn_readfirstlane(rmaskv);
    while (rm) {
        int rr = __ffs(rm) - 1;
        rm &= rm - 1;
        for (int kt = 0; kt < 9; ++kt) {
            // B-fragments: B[k][o], lane: o = lrow (+16 for Ntile1), k = 8*lhi + b
            const unsigned int* tb = tw_h +
                (unsigned)((rr * 9 + kt) * (CIN / 2) + lhi * 4) * COUT + lrow;
            unsigned int bu0[4], bu1[4];
#pragma unroll
            for (int jj = 0; jj < 4; ++jj) {
                bu0[jj] = tb[jj * COUT];
                bu1[jj] = tb[jj * COUT + 16];
            }
            uint4 b0q = make_uint4(bu0[0], bu0[1], bu0[2], bu0[3]);
            uint4 b1q = make_uint4(bu1[0], bu1[1], bu1[2], bu1[3]);
            f16x8 bf0 = __builtin_bit_cast(f16x8, b0q);
            f16x8 bf1 = __builtin_bit_cast(f16x8, b1q);

#pragma unroll
            for (int mt = 0; mt < 4; ++mt) {
                int px = (wid * 4 + mt) * 16 + lrow;   // A row = lane&15
                uint2 wv = Wl[kt * 256 + px];
                int lqr = (int)LQ[kt * 256 + px];
                int lq = lqr & 0xFFF;
                unsigned int keep = ((lqr >> 12) == rr) ? 0xFFFFFFFFu : 0u;
                h2 wpa = __builtin_bit_cast(h2, wv.x);
                h2 wpb = __builtin_bit_cast(h2, wv.y);
                h2 w00h = __builtin_shufflevector(wpa, wpa, 0, 0);
                h2 w01h = __builtin_shufflevector(wpa, wpa, 1, 1);
                h2 w10h = __builtin_shufflevector(wpb, wpb, 0, 0);
                h2 w11h = __builtin_shufflevector(wpb, wpb, 1, 1);
                unsigned int au[4];
#pragma unroll
                for (int j = 0; j < 4; ++j) {          // channel pairs 4*lhi+j
                    int lb = (lhi * 4 + j) * CHS2 + lq;
                    h2 v00 = __builtin_bit_cast(h2, Lx[lb]);
                    h2 v01 = __builtin_bit_cast(h2, Lx[lb + 1]);
                    h2 v10 = __builtin_bit_cast(h2, Lx[lb + WROW]);
                    h2 v11 = __builtin_bit_cast(h2, Lx[lb + WROW + 1]);
                    h2 s = w00h * v00 + w01h * v01 + w10h * v10 + w11h * v11;
                    au[j] = __builtin_bit_cast(unsigned int, s) & keep;
                }
                uint4 aq = make_uint4(au[0], au[1], au[2], au[3]);
                f16x8 af = __builtin_bit_cast(f16x8, aq);
                acc[mt][0] = __builtin_amdgcn_mfma_f32_16x16x32_f16(af, bf0, acc[mt][0], 0, 0, 0);
                acc[mt][1] = __builtin_amdgcn_mfma_f32_16x16x32_f16(af, bf1, acc[mt][1], 0, 0, 0);
            }
        }
    }

    // epilogue: D col = lane&15 (o), row = 4*(lane>>4)+q (tx), Mtile = ty row
    int Xs = bx * 16 + lhi * 4;
#pragma unroll
    for (int mt = 0; mt < 4; ++mt) {
        int Yg = by * 16 + wid * 4 + mt;
#pragma unroll
        for (int nt = 0; nt < 2; ++nt) {
            float* op = out + (nt * 16 + lrow) * HW + Yg * IMG + Xs;
#pragma unroll
            for (int q = 0; q < 4; ++q)
                op[q] = fmaxf(acc[mt][nt][q], 0.0f);
        }
    }
}

extern "C" void kernel_launch(void* const* d_in, const int* in_sizes, int n_in,
                              void* d_out, int out_size, void* d_ws, size_t ws_size,
                              hipStream_t stream) {
    const float* x      = (const float*)d_in[0];
    const float* weight = (const float*)d_in[1];
    const float* offw   = (const float*)d_in[2];
    const float* offb   = (const float*)d_in[3];
    const float* mskw   = (const float*)d_in[4];
    const float* mskb   = (const float*)d_in[5];
    const float* gm     = (const float*)d_in[6];
    float* out = (float*)d_out;

    unsigned int* tw_h = (unsigned int*)d_ws;                   // 147456 B
    unsigned int* owm  = (unsigned int*)((char*)d_ws + 147456); // 15552 B
    float* om = (float*)((char*)d_ws + 294912);                 // 27*HW*4 = 28.3 MB

    build_tw_kernel<<<2, 256, 0, stream>>>(weight, tw_h);
    pack_owm_kernel<<<2, 256, 0, stream>>>(offw, mskw, owm);

    const int tiles = (IMG / TS) * (IMG / TS); // 1024
    offset_mask_kernel<<<tiles, 256, 0, stream>>>(x, owm, offb, mskb, om);
    deform_mfma_kernel<<<tiles, 256, 0, stream>>>(x, om, gm, tw_h, out);
}

// Round 15
// 117.355 us; speedup vs baseline: 1.9858x; 1.1554x over previous
//
#include <hip/hip_runtime.h>

#define IMG 512
#define CIN 32
#define COUT 32
#define NORI 8
#define HW (IMG*IMG)

#define TS 16

// ---- K1 staging geometry (halo 1), f16 channel-pair cells ----
#define W1 18
#define WR1 19
#define CHS1 (W1*WR1)
// ---- K2 staging geometry (halo 4), f16 channel-pair cells ----
#define HALO 4
#define WIN 24
#define WROW 25
#define CHSP 601           // padded plane stride: 601%32=25 -> lhi groups hit different banks

typedef _Float16 h2 __attribute__((ext_vector_type(2)));
typedef __fp16  fp16v2 __attribute__((ext_vector_type(2)));
typedef _Float16 f16x8 __attribute__((ext_vector_type(8)));
typedef float    f32x4 __attribute__((ext_vector_type(4)));

__device__ __forceinline__ float dot2acc(unsigned int a, unsigned int b, float c) {
#if __has_builtin(__builtin_amdgcn_fdot2)
    return __builtin_amdgcn_fdot2(__builtin_bit_cast(h2, a),
                                  __builtin_bit_cast(h2, b), c, false);
#else
    h2 av = __builtin_bit_cast(h2, a), bv = __builtin_bit_cast(h2, b);
    return fmaf((float)av[0], (float)bv[0], fmaf((float)av[1], (float)bv[1], c));
#endif
}

__device__ __forceinline__ unsigned int packh2(float a, float b) {
#if __has_builtin(__builtin_amdgcn_cvt_pkrtz)
    fp16v2 r = __builtin_amdgcn_cvt_pkrtz(a, b);
    return __builtin_bit_cast(unsigned int, r);
#else
    h2 r; r[0] = (_Float16)a; r[1] = (_Float16)b;
    return __builtin_bit_cast(unsigned int, r);
#endif
}

__device__ __forceinline__ unsigned int packh2_rne(float a, float b) {
    h2 r; r[0] = (_Float16)a; r[1] = (_Float16)b;   // RNE casts
    return __builtin_bit_cast(unsigned int, r);
}

#define GEMV8(TP, S2) do {                                             \
    const uint4* _tp = (TP);                                           \
    _Pragma("unroll")                                                  \
    for (int q = 0; q < 8; ++q) {                                      \
        uint4 u = _tp[q];                                              \
        oacc[q * 4 + 0] = dot2acc((S2), u.x, oacc[q * 4 + 0]);         \
        oacc[q * 4 + 1] = dot2acc((S2), u.y, oacc[q * 4 + 1]);         \
        oacc[q * 4 + 2] = dot2acc((S2), u.z, oacc[q * 4 + 2]);         \
        oacc[q * 4 + 3] = dot2acc((S2), u.w, oacc[q * 4 + 3]);         \
    }                                                                  \
} while (0)

// tw_h layout (uint = h2 = channel pair): tw_h[((r*9 + k)*(CIN/2) + cp)*COUT + o]
__global__ void build_tw_kernel(const float* __restrict__ weight, unsigned int* __restrict__ tw_h) {
    int idx = blockIdx.x * blockDim.x + threadIdx.x; // 0..511
    if (idx >= COUT * (CIN / 2)) return;
    int o = idx & 31, cp = idx >> 5;

    float bb[2][9], w45[2][9];
    const float cs = 0.70710678f;
#pragma unroll
    for (int h = 0; h < 2; ++h) {
        int c = 2 * cp + h;
#pragma unroll
        for (int t = 0; t < 9; ++t) bb[h][t] = weight[(o * CIN + c) * 9 + t];
#pragma unroll
        for (int i = 0; i < 3; ++i) {
#pragma unroll
            for (int j = 0; j < 3; ++j) {
                float ys = cs * (float)(i - 1) + cs * (float)(j - 1) + 1.0f;
                float xs = -cs * (float)(i - 1) + cs * (float)(j - 1) + 1.0f;
                float y0f = floorf(ys), x0f = floorf(xs);
                float wy = ys - y0f, wx = xs - x0f;
                int iy0 = (int)y0f, ix0 = (int)x0f;
                float a = 0.0f;
#pragma unroll
                for (int dy = 0; dy < 2; ++dy) {
#pragma unroll
                    for (int dx = 0; dx < 2; ++dx) {
                        int iy = iy0 + dy, ix = ix0 + dx;
                        float wgt = (dy ? wy : 1.0f - wy) * (dx ? wx : 1.0f - wx);
                        bool valid = (iy >= 0) && (iy < 3) && (ix >= 0) && (ix < 3);
                        int iyc = min(max(iy, 0), 2), ixc = min(max(ix, 0), 2);
                        a += bb[h][iyc * 3 + ixc] * (valid ? wgt : 0.0f);
                    }
                }
                w45[h][i * 3 + j] = a;
            }
        }
    }

#pragma unroll
    for (int r = 0; r < NORI; ++r) {
        int rr = r & 3;
#pragma unroll
        for (int i = 0; i < 3; ++i) {
#pragma unroll
            for (int j = 0; j < 3; ++j) {
                int si, sj;
                if (rr == 0) { si = i;     sj = j;     }
                else if (rr == 1) { si = j;     sj = 2 - i; }
                else if (rr == 2) { si = 2 - i; sj = 2 - j; }
                else { si = 2 - j; sj = i;     }
                float v0 = (r < 4) ? bb[0][si * 3 + sj] : w45[0][si * 3 + sj];
                float v1 = (r < 4) ? bb[1][si * 3 + sj] : w45[1][si * 3 + sj];
                tw_h[(((r * 9) + (i * 3 + j)) * (CIN / 2) + cp) * COUT + o] =
                    packh2_rne(v0, v1);
            }
        }
    }
}

// Pack offset+mask conv weights as f16 channel-pairs
__global__ void pack_owm_kernel(const float* __restrict__ offw, const float* __restrict__ mskw,
                                unsigned int* __restrict__ owm) {
    int idx = blockIdx.x * blockDim.x + threadIdx.x;
    if (idx >= 27 * (CIN / 2)) return;
    int oc = idx % 27, cp = idx / 27;
    const float* src = (oc < 18) ? (offw + oc * CIN * 9) : (mskw + (oc - 18) * CIN * 9);
#pragma unroll
    for (int t = 0; t < 9; ++t)
        owm[(cp * 27 + oc) * 9 + t] = packh2_rne(src[(2 * cp) * 9 + t], src[(2 * cp + 1) * 9 + t]);
}

// K1: unchanged (verified ~40us)
__global__ __launch_bounds__(256, 4) void offset_mask_kernel(
    const float* __restrict__ x,
    const unsigned int* __restrict__ owm,
    const float* __restrict__ offb, const float* __restrict__ mskb,
    float* __restrict__ om)
{
    __shared__ unsigned int Lp[8 * CHS1];

    const int tiles_x = IMG / TS;
    int bid = (int)blockIdx.x;
    bid = (bid % 8) * (1024 / 8) + bid / 8;
    int bx = bid % tiles_x, by = bid / tiles_x;
    int tx = threadIdx.x & 15, ty = threadIdx.x >> 4;
    int X = bx * TS + tx, Y = by * TS + ty;
    int p = Y * IMG + X;
    int y0w = by * TS - 1, x0w = bx * TS - 1;

    float acc[27];
#pragma unroll
    for (int i = 0; i < 18; ++i) acc[i] = offb[i];
#pragma unroll
    for (int i = 0; i < 9; ++i) acc[18 + i] = mskb[i];

    for (int pb = 0; pb < 2; ++pb) {
        __syncthreads();
        for (int i = threadIdx.x; i < 8 * (W1 * W1); i += 256) {
            int pr = i / (W1 * W1), cell = i % (W1 * W1);
            int rr = cell / W1, cc = cell % W1;
            int gy = y0w + rr, gx = x0w + cc;
            float a = 0.0f, b = 0.0f;
            if ((unsigned)gy < (unsigned)IMG && (unsigned)gx < (unsigned)IMG) {
                const float* x0 = x + ((pb * 8 + pr) * 2) * HW + gy * IMG + gx;
                a = x0[0]; b = x0[HW];
            }
            Lp[pr * CHS1 + rr * WR1 + cc] = packh2_rne(a, b);
        }
        __syncthreads();

        for (int pr = 0; pr < 8; ++pr) {
            int cp = pb * 8 + pr;
            int base = pr * CHS1 + ty * WR1 + tx;
            unsigned int v2[9];
#pragma unroll
            for (int j = 0; j < 3; ++j) {
                v2[j * 3 + 0] = Lp[base + j * WR1 + 0];
                v2[j * 3 + 1] = Lp[base + j * WR1 + 1];
                v2[j * 3 + 2] = Lp[base + j * WR1 + 2];
            }
            const unsigned int* wp = owm + cp * 27 * 9;   // wave-uniform -> s_load
#pragma unroll
            for (int oc = 0; oc < 27; ++oc)
#pragma unroll
                for (int t = 0; t < 9; ++t)
                    acc[oc] = dot2acc(v2[t], wp[oc * 9 + t], acc[oc]);
        }
    }

    acc[8] = 0.0f; acc[9] = 0.0f; acc[22] = 0.0f;
#pragma unroll
    for (int oc = 0; oc < 18; ++oc) om[oc * HW + p] = acc[oc];
#pragma unroll
    for (int mk = 0; mk < 9; ++mk)
        om[(18 + mk) * HW + p] = 1.0f / (1.0f + __expf(-acc[18 + mk]));
}

// K2 (MFMA, v2): vs R14 — (1) Lx plane stride padded 600->601 (kills the 4-way
// lhi bank alias on A-assembly ds_reads); (2) taps processed in 3 groups of 3
// so Wl/LQ shrink 23KB->7.7KB, total LDS 61.9->46.2KB -> 3 blocks/CU; slow
// flag decided by a cheap 9-tap pre-pass before the group loop.
__global__ __launch_bounds__(256, 3) void deform_mfma_kernel(
    const float* __restrict__ x,
    const float* __restrict__ om,
    const float* __restrict__ gm,
    const unsigned int* __restrict__ tw_h,
    float* __restrict__ out)
{
    __shared__ unsigned int Lx[16 * CHSP];      // 38464 B
    __shared__ uint2 Wl[3 * 256];               // 6144 B
    __shared__ unsigned short LQ[3 * 256];      // 1536 B
    __shared__ int flags[2];                    // [0]=rmask, [1]=anyslow

    const int tiles_x = IMG / TS;
    int bid = (int)blockIdx.x;
    bid = (bid % 8) * (1024 / 8) + bid / 8;
    int bx = bid % tiles_x, by = bid / tiles_x;
    int tid = threadIdx.x;
    int tx = tid & 15, ty = tid >> 4;
    int X = bx * TS + tx, Y = by * TS + ty;
    int p = Y * IMG + X;
    int y0w = by * TS - HALO, x0w = bx * TS - HALO;

    if (tid < 2) flags[tid] = 0;
    __syncthreads();

    // stage all 32 channels as f16 pairs (RNE), padded plane stride
    for (int i = tid; i < 16 * (WIN * WIN); i += 256) {
        int pr = i / (WIN * WIN), cell = i % (WIN * WIN);
        int rr = cell / WIN, cc = cell % WIN;
        int gy = y0w + rr, gx = x0w + cc;
        float a = 0.0f, b = 0.0f;
        if ((unsigned)gy < (unsigned)IMG && (unsigned)gx < (unsigned)IMG) {
            const float* x0 = x + (2 * pr) * HW + gy * IMG + gx;
            a = x0[0]; b = x0[HW];
        }
        Lx[pr * CHSP + rr * WROW + cc] = packh2_rne(a, b);
    }

    int r = 0;
#pragma unroll
    for (int n = 1; n < NORI; ++n) r = (gm[n * HW + p] > 0.5f) ? n : r;

    // pre-pass: block-wide slow detection for all 9 taps
    bool slow = false;
    for (int kt = 0; kt < 9; ++kt) {
        int ky = kt / 3, kx = kt - ky * 3;
        float offy = om[(2 * kt) * HW + p];
        float offx = om[(2 * kt + 1) * HW + p];
        float pyf = (float)(Y - 1 + ky) + offy;
        float pxf = (float)(X - 1 + kx) + offx;
        int iy0 = (int)floorf(pyf), ix0 = (int)floorf(pxf);
        int ryu = iy0 - y0w, rxu = ix0 - x0w;
        slow |= !(((unsigned)ryu < (WIN - 1)) && ((unsigned)rxu < (WIN - 1)));
    }
    atomicOr(&flags[0], 1 << r);
    if (slow) flags[1] = 1;   // same-value race OK
    __syncthreads();

    int rmaskv = __builtin_amdgcn_readfirstlane(flags[0]);
    int anyslow = flags[1];

    if (anyslow) {
        // whole-block exact path (rare): per-thread f32, clamped global reads
        float oacc[32];
#pragma unroll
        for (int o = 0; o < 32; ++o) oacc[o] = 0.0f;
        for (int kt = 0; kt < 9; ++kt) {
            int ky = kt / 3, kx = kt - ky * 3;
            float offy = om[(2 * kt) * HW + p];
            float offx = om[(2 * kt + 1) * HW + p];
            float m    = om[(18 + kt) * HW + p];
            float pyf = (float)(Y - 1 + ky) + offy;
            float pxf = (float)(X - 1 + kx) + offx;
            float y0f = floorf(pyf), x0f = floorf(pxf);
            float wy = pyf - y0f, wx = pxf - x0f;
            int iy0 = (int)y0f, ix0 = (int)x0f;
            float vy0 = ((unsigned)iy0 < (unsigned)IMG) ? 1.0f : 0.0f;
            float vy1 = ((unsigned)(iy0 + 1) < (unsigned)IMG) ? 1.0f : 0.0f;
            float vx0 = ((unsigned)ix0 < (unsigned)IMG) ? 1.0f : 0.0f;
            float vx1 = ((unsigned)(ix0 + 1) < (unsigned)IMG) ? 1.0f : 0.0f;
            float w00 = m * (1.0f - wy) * (1.0f - wx) * vy0 * vx0;
            float w01 = m * (1.0f - wy) * wx * vy0 * vx1;
            float w10 = m * wy * (1.0f - wx) * vy1 * vx0;
            float w11 = m * wy * wx * vy1 * vx1;
            int cy0 = min(max(iy0, 0), IMG - 1), cy1 = min(max(iy0 + 1, 0), IMG - 1);
            int cx0 = min(max(ix0, 0), IMG - 1), cx1 = min(max(ix0 + 1, 0), IMG - 1);
            int g00 = cy0 * IMG + cx0, g01 = cy0 * IMG + cx1;
            int g10 = cy1 * IMG + cx0, g11 = cy1 * IMG + cx1;
            const uint4* tp = (const uint4*)(tw_h + (unsigned)((r * 9 + kt) * (CIN / 2)) * COUT);
            for (int cp = 0; cp < CIN / 2; ++cp) {
                const float* xc0 = x + (2 * cp) * HW;
                const float* xc1 = xc0 + HW;
                float s0 = fmaf(w00, xc0[g00], fmaf(w01, xc0[g01],
                           fmaf(w10, xc0[g10], w11 * xc0[g11])));
                float s1 = fmaf(w00, xc1[g00], fmaf(w01, xc1[g01],
                           fmaf(w10, xc1[g10], w11 * xc1[g11])));
                unsigned int s2 = packh2(s0, s1);
                GEMV8(tp + cp * 8, s2);
            }
        }
#pragma unroll
        for (int o = 0; o < 32; ++o) out[o * HW + p] = fmaxf(oacc[o], 0.0f);
        return;
    }

    // ---- MFMA path, tap-groups of 3 ----
    int lane = tid & 63, wid = tid >> 6;
    int lrow = lane & 15, lhi = lane >> 4;

    f32x4 acc[4][2] = {};

    for (int g = 0; g < 3; ++g) {
        // phase 1 (this group): per-(pixel,tap) bilinear weights + index -> LDS
#pragma unroll
        for (int kt2 = 0; kt2 < 3; ++kt2) {
            int kt = g * 3 + kt2;
            int ky = kt / 3, kx = kt - ky * 3;
            float offy = om[(2 * kt) * HW + p];
            float offx = om[(2 * kt + 1) * HW + p];
            float m    = om[(18 + kt) * HW + p];
            float pyf = (float)(Y - 1 + ky) + offy;
            float pxf = (float)(X - 1 + kx) + offx;
            float y0f = floorf(pyf), x0f = floorf(pxf);
            float wy = pyf - y0f, wx = pxf - x0f;
            int iy0 = (int)y0f, ix0 = (int)x0f;
            float vy0 = ((unsigned)iy0 < (unsigned)IMG) ? 1.0f : 0.0f;
            float vy1 = ((unsigned)(iy0 + 1) < (unsigned)IMG) ? 1.0f : 0.0f;
            float vx0 = ((unsigned)ix0 < (unsigned)IMG) ? 1.0f : 0.0f;
            float vx1 = ((unsigned)(ix0 + 1) < (unsigned)IMG) ? 1.0f : 0.0f;
            float w00 = m * (1.0f - wy) * (1.0f - wx) * vy0 * vx0;
            float w01 = m * (1.0f - wy) * wx * vy0 * vx1;
            float w10 = m * wy * (1.0f - wx) * vy1 * vx0;
            float w11 = m * wy * wx * vy1 * vx1;
            int lq = (iy0 - y0w) * WROW + (ix0 - x0w);
            Wl[kt2 * 256 + tid] = make_uint2(packh2_rne(w00, w01), packh2_rne(w10, w11));
            LQ[kt2 * 256 + tid] = (unsigned short)(lq | (r << 12));
        }
        __syncthreads();

        // phase 2: sector loop x 3 taps x 4 Mtiles x 2 Ntiles
        int rm = rmaskv;
        while (rm) {
            int rr = __ffs(rm) - 1;
            rm &= rm - 1;
#pragma unroll
            for (int kt2 = 0; kt2 < 3; ++kt2) {
                int kt = g * 3 + kt2;
                // B-fragments: lane o = lrow (+16 Ntile1), k = 8*lhi + b
                const unsigned int* tb = tw_h +
                    (unsigned)((rr * 9 + kt) * (CIN / 2) + lhi * 4) * COUT + lrow;
                unsigned int bu0[4], bu1[4];
#pragma unroll
                for (int jj = 0; jj < 4; ++jj) {
                    bu0[jj] = tb[jj * COUT];
                    bu1[jj] = tb[jj * COUT + 16];
                }
                uint4 b0q = make_uint4(bu0[0], bu0[1], bu0[2], bu0[3]);
                uint4 b1q = make_uint4(bu1[0], bu1[1], bu1[2], bu1[3]);
                f16x8 bf0 = __builtin_bit_cast(f16x8, b0q);
                f16x8 bf1 = __builtin_bit_cast(f16x8, b1q);

#pragma unroll
                for (int mt = 0; mt < 4; ++mt) {
                    int px = (wid * 4 + mt) * 16 + lrow;   // A row = lane&15
                    uint2 wv = Wl[kt2 * 256 + px];
                    int lqr = (int)LQ[kt2 * 256 + px];
                    int lq = lqr & 0xFFF;
                    unsigned int keep = ((lqr >> 12) == rr) ? 0xFFFFFFFFu : 0u;
                    h2 wpa = __builtin_bit_cast(h2, wv.x);
                    h2 wpb = __builtin_bit_cast(h2, wv.y);
                    h2 w00h = __builtin_shufflevector(wpa, wpa, 0, 0);
                    h2 w01h = __builtin_shufflevector(wpa, wpa, 1, 1);
                    h2 w10h = __builtin_shufflevector(wpb, wpb, 0, 0);
                    h2 w11h = __builtin_shufflevector(wpb, wpb, 1, 1);
                    unsigned int au[4];
#pragma unroll
                    for (int j = 0; j < 4; ++j) {          // channel pairs 4*lhi+j
                        int lb = (lhi * 4 + j) * CHSP + lq;
                        h2 v00 = __builtin_bit_cast(h2, Lx[lb]);
                        h2 v01 = __builtin_bit_cast(h2, Lx[lb + 1]);
                        h2 v10 = __builtin_bit_cast(h2, Lx[lb + WROW]);
                        h2 v11 = __builtin_bit_cast(h2, Lx[lb + WROW + 1]);
                        h2 s = w00h * v00 + w01h * v01 + w10h * v10 + w11h * v11;
                        au[j] = __builtin_bit_cast(unsigned int, s) & keep;
                    }
                    uint4 aq = make_uint4(au[0], au[1], au[2], au[3]);
                    f16x8 af = __builtin_bit_cast(f16x8, aq);
                    acc[mt][0] = __builtin_amdgcn_mfma_f32_16x16x32_f16(af, bf0, acc[mt][0], 0, 0, 0);
                    acc[mt][1] = __builtin_amdgcn_mfma_f32_16x16x32_f16(af, bf1, acc[mt][1], 0, 0, 0);
                }
            }
        }
        __syncthreads();   // before next group overwrites Wl/LQ
    }

    // epilogue: D col = lane&15 (o), row = 4*(lane>>4)+q (x), Mtile rows via wid
    int Xs = bx * 16 + lhi * 4;
#pragma unroll
    for (int mt = 0; mt < 4; ++mt) {
        int Yg = by * 16 + wid * 4 + mt;
#pragma unroll
        for (int nt = 0; nt < 2; ++nt) {
            float* op = out + (nt * 16 + lrow) * HW + Yg * IMG + Xs;
#pragma unroll
            for (int q = 0; q < 4; ++q)
                op[q] = fmaxf(acc[mt][nt][q], 0.0f);
        }
    }
}

extern "C" void kernel_launch(void* const* d_in, const int* in_sizes, int n_in,
                              void* d_out, int out_size, void* d_ws, size_t ws_size,
                              hipStream_t stream) {
    const float* x      = (const float*)d_in[0];
    const float* weight = (const float*)d_in[1];
    const float* offw   = (const float*)d_in[2];
    const float* offb   = (const float*)d_in[3];
    const float* mskw   = (const float*)d_in[4];
    const float* mskb   = (const float*)d_in[5];
    const float* gm     = (const float*)d_in[6];
    float* out = (float*)d_out;

    unsigned int* tw_h = (unsigned int*)d_ws;                   // 147456 B
    unsigned int* owm  = (unsigned int*)((char*)d_ws + 147456); // 15552 B
    float* om = (float*)((char*)d_ws + 294912);                 // 27*HW*4 = 28.3 MB

    build_tw_kernel<<<2, 256, 0, stream>>>(weight, tw_h);
    pack_owm_kernel<<<2, 256, 0, stream>>>(offw, mskw, owm);

    const int tiles = (IMG / TS) * (IMG / TS); // 1024
    offset_mask_kernel<<<tiles, 256, 0, stream>>>(x, owm, offb, mskb, om);
    deform_mfma_kernel<<<tiles, 256, 0, stream>>>(x, om, gm, tw_h, out);
}

// Round 16
// 95.622 us; speedup vs baseline: 2.4371x; 1.2273x over previous
//
#include <hip/hip_runtime.h>

#define IMG 512
#define CIN 32
#define COUT 32
#define NORI 8
#define HW (IMG*IMG)

#define TS 16

// ---- K1 staging geometry (halo 1), f16 channel-pair cells ----
#define W1 18
#define WR1 19
#define CHS1P 346          // padded plane stride: 4*346%32==8 -> lhi offsets 0,8,16,24
// ---- K2 staging geometry (halo 4), f16 channel-pair cells ----
#define HALO 4
#define WIN 24
#define WROW 25
#define CHSP 602           // padded plane stride: 4*602%32==8 -> lhi offsets 0,8,16,24

typedef _Float16 h2 __attribute__((ext_vector_type(2)));
typedef __fp16  fp16v2 __attribute__((ext_vector_type(2)));
typedef _Float16 f16x8 __attribute__((ext_vector_type(8)));
typedef float    f32x4 __attribute__((ext_vector_type(4)));

__device__ __forceinline__ float dot2acc(unsigned int a, unsigned int b, float c) {
#if __has_builtin(__builtin_amdgcn_fdot2)
    return __builtin_amdgcn_fdot2(__builtin_bit_cast(h2, a),
                                  __builtin_bit_cast(h2, b), c, false);
#else
    h2 av = __builtin_bit_cast(h2, a), bv = __builtin_bit_cast(h2, b);
    return fmaf((float)av[0], (float)bv[0], fmaf((float)av[1], (float)bv[1], c));
#endif
}

__device__ __forceinline__ unsigned int packh2(float a, float b) {
#if __has_builtin(__builtin_amdgcn_cvt_pkrtz)
    fp16v2 r = __builtin_amdgcn_cvt_pkrtz(a, b);
    return __builtin_bit_cast(unsigned int, r);
#else
    h2 r; r[0] = (_Float16)a; r[1] = (_Float16)b;
    return __builtin_bit_cast(unsigned int, r);
#endif
}

__device__ __forceinline__ unsigned int packh2_rne(float a, float b) {
    h2 r; r[0] = (_Float16)a; r[1] = (_Float16)b;   // RNE casts
    return __builtin_bit_cast(unsigned int, r);
}

#define GEMV8(TP, S2) do {                                             \
    const uint4* _tp = (TP);                                           \
    _Pragma("unroll")                                                  \
    for (int q = 0; q < 8; ++q) {                                      \
        uint4 u = _tp[q];                                              \
        oacc[q * 4 + 0] = dot2acc((S2), u.x, oacc[q * 4 + 0]);         \
        oacc[q * 4 + 1] = dot2acc((S2), u.y, oacc[q * 4 + 1]);         \
        oacc[q * 4 + 2] = dot2acc((S2), u.z, oacc[q * 4 + 2]);         \
        oacc[q * 4 + 3] = dot2acc((S2), u.w, oacc[q * 4 + 3]);         \
    }                                                                  \
} while (0)

// tw_h layout (uint = h2 = channel pair): tw_h[((r*9 + k)*(CIN/2) + cp)*COUT + o]
__global__ void build_tw_kernel(const float* __restrict__ weight, unsigned int* __restrict__ tw_h) {
    int idx = blockIdx.x * blockDim.x + threadIdx.x; // 0..511
    if (idx >= COUT * (CIN / 2)) return;
    int o = idx & 31, cp = idx >> 5;

    float bb[2][9], w45[2][9];
    const float cs = 0.70710678f;
#pragma unroll
    for (int h = 0; h < 2; ++h) {
        int c = 2 * cp + h;
#pragma unroll
        for (int t = 0; t < 9; ++t) bb[h][t] = weight[(o * CIN + c) * 9 + t];
#pragma unroll
        for (int i = 0; i < 3; ++i) {
#pragma unroll
            for (int j = 0; j < 3; ++j) {
                float ys = cs * (float)(i - 1) + cs * (float)(j - 1) + 1.0f;
                float xs = -cs * (float)(i - 1) + cs * (float)(j - 1) + 1.0f;
                float y0f = floorf(ys), x0f = floorf(xs);
                float wy = ys - y0f, wx = xs - x0f;
                int iy0 = (int)y0f, ix0 = (int)x0f;
                float a = 0.0f;
#pragma unroll
                for (int dy = 0; dy < 2; ++dy) {
#pragma unroll
                    for (int dx = 0; dx < 2; ++dx) {
                        int iy = iy0 + dy, ix = ix0 + dx;
                        float wgt = (dy ? wy : 1.0f - wy) * (dx ? wx : 1.0f - wx);
                        bool valid = (iy >= 0) && (iy < 3) && (ix >= 0) && (ix < 3);
                        int iyc = min(max(iy, 0), 2), ixc = min(max(ix, 0), 2);
                        a += bb[h][iyc * 3 + ixc] * (valid ? wgt : 0.0f);
                    }
                }
                w45[h][i * 3 + j] = a;
            }
        }
    }

#pragma unroll
    for (int r = 0; r < NORI; ++r) {
        int rr = r & 3;
#pragma unroll
        for (int i = 0; i < 3; ++i) {
#pragma unroll
            for (int j = 0; j < 3; ++j) {
                int si, sj;
                if (rr == 0) { si = i;     sj = j;     }
                else if (rr == 1) { si = j;     sj = 2 - i; }
                else if (rr == 2) { si = 2 - i; sj = 2 - j; }
                else { si = 2 - j; sj = i;     }
                float v0 = (r < 4) ? bb[0][si * 3 + sj] : w45[0][si * 3 + sj];
                float v1 = (r < 4) ? bb[1][si * 3 + sj] : w45[1][si * 3 + sj];
                tw_h[(((r * 9) + (i * 3 + j)) * (CIN / 2) + cp) * COUT + o] =
                    packh2_rne(v0, v1);
            }
        }
    }
}

// Pack offset+mask conv weights in MFMA B-fragment layout:
// owmb[(kt*16 + cp)*32 + oc] = h2( w[oc][2cp][kt], w[oc][2cp+1][kt] ), oc>=27 -> 0
__global__ void pack_owmb_kernel(const float* __restrict__ offw, const float* __restrict__ mskw,
                                 unsigned int* __restrict__ owmb) {
    int idx = blockIdx.x * blockDim.x + threadIdx.x; // 9*16*32 = 4608
    if (idx >= 9 * 16 * 32) return;
    int oc = idx & 31;
    int cp = (idx >> 5) & 15;
    int kt = idx >> 9;
    float v0 = 0.0f, v1 = 0.0f;
    if (oc < 18) {
        v0 = offw[(oc * CIN + 2 * cp) * 9 + kt];
        v1 = offw[(oc * CIN + 2 * cp + 1) * 9 + kt];
    } else if (oc < 27) {
        v0 = mskw[((oc - 18) * CIN + 2 * cp) * 9 + kt];
        v1 = mskw[((oc - 18) * CIN + 2 * cp + 1) * 9 + kt];
    }
    owmb[(kt * 16 + cp) * 32 + oc] = packh2_rne(v0, v1);
}

// K1 (MFMA): om[256px,27oc] = sum_kt X_kt[256px,32c] x W_kt[32c,27oc].
// Static taps -> A-assembly is one ds_read_b32 per fragment uint. Same
// verified fragment layouts as K2's MFMA. Epilogue: bias + fixups + sigmoid.
__global__ __launch_bounds__(256, 4) void offset_mask_mfma_kernel(
    const float* __restrict__ x,
    const unsigned int* __restrict__ owmb,
    const float* __restrict__ offb, const float* __restrict__ mskb,
    float* __restrict__ om)
{
    __shared__ unsigned int Lp[16 * CHS1P];   // 22144 B

    const int tiles_x = IMG / TS;
    int bid = (int)blockIdx.x;
    bid = (bid % 8) * (1024 / 8) + bid / 8;
    int bx = bid % tiles_x, by = bid / tiles_x;
    int tid = threadIdx.x;
    int y0w = by * TS - 1, x0w = bx * TS - 1;

    for (int i = tid; i < 16 * (W1 * W1); i += 256) {
        int pr = i / (W1 * W1), cell = i % (W1 * W1);
        int rr = cell / W1, cc = cell % W1;
        int gy = y0w + rr, gx = x0w + cc;
        float a = 0.0f, b = 0.0f;
        if ((unsigned)gy < (unsigned)IMG && (unsigned)gx < (unsigned)IMG) {
            const float* x0 = x + (2 * pr) * HW + gy * IMG + gx;
            a = x0[0]; b = x0[HW];
        }
        Lp[pr * CHS1P + rr * WR1 + cc] = packh2_rne(a, b);
    }
    __syncthreads();

    int lane = tid & 63, wid = tid >> 6;
    int lrow = lane & 15, lhi = lane >> 4;

    f32x4 acc[4][2] = {};

#pragma unroll
    for (int kt = 0; kt < 9; ++kt) {
        const int ky = kt / 3, kx = kt % 3;
        // B-fragments: lane oc = lrow (+16 Ntile1), k = 8*lhi + b
        const unsigned int* tb = owmb + (kt * 16 + lhi * 4) * 32 + lrow;
        unsigned int bu0[4], bu1[4];
#pragma unroll
        for (int jj = 0; jj < 4; ++jj) {
            bu0[jj] = tb[jj * 32];
            bu1[jj] = tb[jj * 32 + 16];
        }
        uint4 b0q = make_uint4(bu0[0], bu0[1], bu0[2], bu0[3]);
        uint4 b1q = make_uint4(bu1[0], bu1[1], bu1[2], bu1[3]);
        f16x8 bf0 = __builtin_bit_cast(f16x8, b0q);
        f16x8 bf1 = __builtin_bit_cast(f16x8, b1q);

#pragma unroll
        for (int mt = 0; mt < 4; ++mt) {
            int yy = wid * 4 + mt;                       // pixel y, x = lrow
            int lq = (yy + ky) * WR1 + (lrow + kx);
            unsigned int au[4];
#pragma unroll
            for (int j = 0; j < 4; ++j)
                au[j] = Lp[(lhi * 4 + j) * CHS1P + lq];
            uint4 aq = make_uint4(au[0], au[1], au[2], au[3]);
            f16x8 af = __builtin_bit_cast(f16x8, aq);
            acc[mt][0] = __builtin_amdgcn_mfma_f32_16x16x32_f16(af, bf0, acc[mt][0], 0, 0, 0);
            acc[mt][1] = __builtin_amdgcn_mfma_f32_16x16x32_f16(af, bf1, acc[mt][1], 0, 0, 0);
        }
    }

    // epilogue: D col = oc (lane&15 / +16), row = pixel x = 4*lhi+q
    float bias_n0 = offb[lrow];                              // oc = lrow < 16
    float bias_n1 = (lrow < 2) ? offb[16 + lrow]
                  : ((lrow < 11) ? mskb[lrow - 2] : 0.0f);   // oc = 16+lrow
    int Xs = bx * 16 + lhi * 4;
#pragma unroll
    for (int mt = 0; mt < 4; ++mt) {
        int Yg = by * 16 + wid * 4 + mt;
        {   // nt=0: oc 0..15 (offset channels); ch 8,9 forced 0
            int oc = lrow;
            float* op = om + oc * HW + Yg * IMG + Xs;
            bool zero = (oc == 8) || (oc == 9);
#pragma unroll
            for (int q = 0; q < 4; ++q)
                op[q] = zero ? 0.0f : (acc[mt][0][q] + bias_n0);
        }
        {   // nt=1: oc 16..26; >=18 are mask channels (sigmoid), ch22 -> 0.5
            int oc = 16 + lrow;
            if (oc < 27) {
                float* op = om + oc * HW + Yg * IMG + Xs;
#pragma unroll
                for (int q = 0; q < 4; ++q) {
                    float t = acc[mt][1][q] + bias_n1;
                    if (oc >= 18) t = (oc == 22) ? 0.5f : 1.0f / (1.0f + __expf(-t));
                    op[q] = t;
                }
            }
        }
    }
}

// K2 (MFMA): unchanged from R15 except CHSP 601->602 (lhi bank offsets
// 0,8,16,24 instead of 0,4,8,12 -> overlap drops to free 2-way).
__global__ __launch_bounds__(256, 3) void deform_mfma_kernel(
    const float* __restrict__ x,
    const float* __restrict__ om,
    const float* __restrict__ gm,
    const unsigned int* __restrict__ tw_h,
    float* __restrict__ out)
{
    __shared__ unsigned int Lx[16 * CHSP];      // 38528 B
    __shared__ uint2 Wl[3 * 256];               // 6144 B
    __shared__ unsigned short LQ[3 * 256];      // 1536 B
    __shared__ int flags[2];                    // [0]=rmask, [1]=anyslow

    const int tiles_x = IMG / TS;
    int bid = (int)blockIdx.x;
    bid = (bid % 8) * (1024 / 8) + bid / 8;
    int bx = bid % tiles_x, by = bid / tiles_x;
    int tid = threadIdx.x;
    int tx = tid & 15, ty = tid >> 4;
    int X = bx * TS + tx, Y = by * TS + ty;
    int p = Y * IMG + X;
    int y0w = by * TS - HALO, x0w = bx * TS - HALO;

    if (tid < 2) flags[tid] = 0;
    __syncthreads();

    // stage all 32 channels as f16 pairs (RNE), padded plane stride
    for (int i = tid; i < 16 * (WIN * WIN); i += 256) {
        int pr = i / (WIN * WIN), cell = i % (WIN * WIN);
        int rr = cell / WIN, cc = cell % WIN;
        int gy = y0w + rr, gx = x0w + cc;
        float a = 0.0f, b = 0.0f;
        if ((unsigned)gy < (unsigned)IMG && (unsigned)gx < (unsigned)IMG) {
            const float* x0 = x + (2 * pr) * HW + gy * IMG + gx;
            a = x0[0]; b = x0[HW];
        }
        Lx[pr * CHSP + rr * WROW + cc] = packh2_rne(a, b);
    }

    int r = 0;
#pragma unroll
    for (int n = 1; n < NORI; ++n) r = (gm[n * HW + p] > 0.5f) ? n : r;

    // pre-pass: block-wide slow detection for all 9 taps
    bool slow = false;
    for (int kt = 0; kt < 9; ++kt) {
        int ky = kt / 3, kx = kt - ky * 3;
        float offy = om[(2 * kt) * HW + p];
        float offx = om[(2 * kt + 1) * HW + p];
        float pyf = (float)(Y - 1 + ky) + offy;
        float pxf = (float)(X - 1 + kx) + offx;
        int iy0 = (int)floorf(pyf), ix0 = (int)floorf(pxf);
        int ryu = iy0 - y0w, rxu = ix0 - x0w;
        slow |= !(((unsigned)ryu < (WIN - 1)) && ((unsigned)rxu < (WIN - 1)));
    }
    atomicOr(&flags[0], 1 << r);
    if (slow) flags[1] = 1;   // same-value race OK
    __syncthreads();

    int rmaskv = __builtin_amdgcn_readfirstlane(flags[0]);
    int anyslow = flags[1];

    if (anyslow) {
        // whole-block exact path (rare): per-thread f32, clamped global reads
        float oacc[32];
#pragma unroll
        for (int o = 0; o < 32; ++o) oacc[o] = 0.0f;
        for (int kt = 0; kt < 9; ++kt) {
            int ky = kt / 3, kx = kt - ky * 3;
            float offy = om[(2 * kt) * HW + p];
            float offx = om[(2 * kt + 1) * HW + p];
            float m    = om[(18 + kt) * HW + p];
            float pyf = (float)(Y - 1 + ky) + offy;
            float pxf = (float)(X - 1 + kx) + offx;
            float y0f = floorf(pyf), x0f = floorf(pxf);
            float wy = pyf - y0f, wx = pxf - x0f;
            int iy0 = (int)y0f, ix0 = (int)x0f;
            float vy0 = ((unsigned)iy0 < (unsigned)IMG) ? 1.0f : 0.0f;
            float vy1 = ((unsigned)(iy0 + 1) < (unsigned)IMG) ? 1.0f : 0.0f;
            float vx0 = ((unsigned)ix0 < (unsigned)IMG) ? 1.0f : 0.0f;
            float vx1 = ((unsigned)(ix0 + 1) < (unsigned)IMG) ? 1.0f : 0.0f;
            float w00 = m * (1.0f - wy) * (1.0f - wx) * vy0 * vx0;
            float w01 = m * (1.0f - wy) * wx * vy0 * vx1;
            float w10 = m * wy * (1.0f - wx) * vy1 * vx0;
            float w11 = m * wy * wx * vy1 * vx1;
            int cy0 = min(max(iy0, 0), IMG - 1), cy1 = min(max(iy0 + 1, 0), IMG - 1);
            int cx0 = min(max(ix0, 0), IMG - 1), cx1 = min(max(ix0 + 1, 0), IMG - 1);
            int g00 = cy0 * IMG + cx0, g01 = cy0 * IMG + cx1;
            int g10 = cy1 * IMG + cx0, g11 = cy1 * IMG + cx1;
            const uint4* tp = (const uint4*)(tw_h + (unsigned)((r * 9 + kt) * (CIN / 2)) * COUT);
            for (int cp = 0; cp < CIN / 2; ++cp) {
                const float* xc0 = x + (2 * cp) * HW;
                const float* xc1 = xc0 + HW;
                float s0 = fmaf(w00, xc0[g00], fmaf(w01, xc0[g01],
                           fmaf(w10, xc0[g10], w11 * xc0[g11])));
                float s1 = fmaf(w00, xc1[g00], fmaf(w01, xc1[g01],
                           fmaf(w10, xc1[g10], w11 * xc1[g11])));
                unsigned int s2 = packh2(s0, s1);
                GEMV8(tp + cp * 8, s2);
            }
        }
#pragma unroll
        for (int o = 0; o < 32; ++o) out[o * HW + p] = fmaxf(oacc[o], 0.0f);
        return;
    }

    // ---- MFMA path, tap-groups of 3 ----
    int lane = tid & 63, wid = tid >> 6;
    int lrow = lane & 15, lhi = lane >> 4;

    f32x4 acc[4][2] = {};

    for (int g = 0; g < 3; ++g) {
#pragma unroll
        for (int kt2 = 0; kt2 < 3; ++kt2) {
            int kt = g * 3 + kt2;
            int ky = kt / 3, kx = kt - ky * 3;
            float offy = om[(2 * kt) * HW + p];
            float offx = om[(2 * kt + 1) * HW + p];
            float m    = om[(18 + kt) * HW + p];
            float pyf = (float)(Y - 1 + ky) + offy;
            float pxf = (float)(X - 1 + kx) + offx;
            float y0f = floorf(pyf), x0f = floorf(pxf);
            float wy = pyf - y0f, wx = pxf - x0f;
            int iy0 = (int)y0f, ix0 = (int)x0f;
            float vy0 = ((unsigned)iy0 < (unsigned)IMG) ? 1.0f : 0.0f;
            float vy1 = ((unsigned)(iy0 + 1) < (unsigned)IMG) ? 1.0f : 0.0f;
            float vx0 = ((unsigned)ix0 < (unsigned)IMG) ? 1.0f : 0.0f;
            float vx1 = ((unsigned)(ix0 + 1) < (unsigned)IMG) ? 1.0f : 0.0f;
            float w00 = m * (1.0f - wy) * (1.0f - wx) * vy0 * vx0;
            float w01 = m * (1.0f - wy) * wx * vy0 * vx1;
            float w10 = m * wy * (1.0f - wx) * vy1 * vx0;
            float w11 = m * wy * wx * vy1 * vx1;
            int lq = (iy0 - y0w) * WROW + (ix0 - x0w);
            Wl[kt2 * 256 + tid] = make_uint2(packh2_rne(w00, w01), packh2_rne(w10, w11));
            LQ[kt2 * 256 + tid] = (unsigned short)(lq | (r << 12));
        }
        __syncthreads();

        int rm = rmaskv;
        while (rm) {
            int rr = __ffs(rm) - 1;
            rm &= rm - 1;
#pragma unroll
            for (int kt2 = 0; kt2 < 3; ++kt2) {
                int kt = g * 3 + kt2;
                const unsigned int* tb = tw_h +
                    (unsigned)((rr * 9 + kt) * (CIN / 2) + lhi * 4) * COUT + lrow;
                unsigned int bu0[4], bu1[4];
#pragma unroll
                for (int jj = 0; jj < 4; ++jj) {
                    bu0[jj] = tb[jj * COUT];
                    bu1[jj] = tb[jj * COUT + 16];
                }
                uint4 b0q = make_uint4(bu0[0], bu0[1], bu0[2], bu0[3]);
                uint4 b1q = make_uint4(bu1[0], bu1[1], bu1[2], bu1[3]);
                f16x8 bf0 = __builtin_bit_cast(f16x8, b0q);
                f16x8 bf1 = __builtin_bit_cast(f16x8, b1q);

#pragma unroll
                for (int mt = 0; mt < 4; ++mt) {
                    int px = (wid * 4 + mt) * 16 + lrow;
                    uint2 wv = Wl[kt2 * 256 + px];
                    int lqr = (int)LQ[kt2 * 256 + px];
                    int lq = lqr & 0xFFF;
                    unsigned int keep = ((lqr >> 12) == rr) ? 0xFFFFFFFFu : 0u;
                    h2 wpa = __builtin_bit_cast(h2, wv.x);
                    h2 wpb = __builtin_bit_cast(h2, wv.y);
                    h2 w00h = __builtin_shufflevector(wpa, wpa, 0, 0);
                    h2 w01h = __builtin_shufflevector(wpa, wpa, 1, 1);
                    h2 w10h = __builtin_shufflevector(wpb, wpb, 0, 0);
                    h2 w11h = __builtin_shufflevector(wpb, wpb, 1, 1);
                    unsigned int au[4];
#pragma unroll
                    for (int j = 0; j < 4; ++j) {
                        int lb = (lhi * 4 + j) * CHSP + lq;
                        h2 v00 = __builtin_bit_cast(h2, Lx[lb]);
                        h2 v01 = __builtin_bit_cast(h2, Lx[lb + 1]);
                        h2 v10 = __builtin_bit_cast(h2, Lx[lb + WROW]);
                        h2 v11 = __builtin_bit_cast(h2, Lx[lb + WROW + 1]);
                        h2 s = w00h * v00 + w01h * v01 + w10h * v10 + w11h * v11;
                        au[j] = __builtin_bit_cast(unsigned int, s) & keep;
                    }
                    uint4 aq = make_uint4(au[0], au[1], au[2], au[3]);
                    f16x8 af = __builtin_bit_cast(f16x8, aq);
                    acc[mt][0] = __builtin_amdgcn_mfma_f32_16x16x32_f16(af, bf0, acc[mt][0], 0, 0, 0);
                    acc[mt][1] = __builtin_amdgcn_mfma_f32_16x16x32_f16(af, bf1, acc[mt][1], 0, 0, 0);
                }
            }
        }
        __syncthreads();   // before next group overwrites Wl/LQ
    }

    // epilogue
    int Xs = bx * 16 + lhi * 4;
#pragma unroll
    for (int mt = 0; mt < 4; ++mt) {
        int Yg = by * 16 + wid * 4 + mt;
#pragma unroll
        for (int nt = 0; nt < 2; ++nt) {
            float* op = out + (nt * 16 + lrow) * HW + Yg * IMG + Xs;
#pragma unroll
            for (int q = 0; q < 4; ++q)
                op[q] = fmaxf(acc[mt][nt][q], 0.0f);
        }
    }
}

extern "C" void kernel_launch(void* const* d_in, const int* in_sizes, int n_in,
                              void* d_out, int out_size, void* d_ws, size_t ws_size,
                              hipStream_t stream) {
    const float* x      = (const float*)d_in[0];
    const float* weight = (const float*)d_in[1];
    const float* offw   = (const float*)d_in[2];
    const float* offb   = (const float*)d_in[3];
    const float* mskw   = (const float*)d_in[4];
    const float* mskb   = (const float*)d_in[5];
    const float* gm     = (const float*)d_in[6];
    float* out = (float*)d_out;

    unsigned int* tw_h = (unsigned int*)d_ws;                   // 147456 B
    unsigned int* owmb = (unsigned int*)((char*)d_ws + 147456); // 18432 B
    float* om = (float*)((char*)d_ws + 294912);                 // 27*HW*4 = 28.3 MB

    build_tw_kernel<<<2, 256, 0, stream>>>(weight, tw_h);
    pack_owmb_kernel<<<18, 256, 0, stream>>>(offw, mskw, owmb);

    const int tiles = (IMG / TS) * (IMG / TS); // 1024
    offset_mask_mfma_kernel<<<tiles, 256, 0, stream>>>(x, owmb, offb, mskb, om);
    deform_mfma_kernel<<<tiles, 256, 0, stream>>>(x, om, gm, tw_h, out);
}

// Round 17
// 85.599 us; speedup vs baseline: 2.7224x; 1.1171x over previous
//
#include <hip/hip_runtime.h>

#define IMG 512
#define CIN 32
#define COUT 32
#define NORI 8
#define HW (IMG*IMG)

#define TS 16

// ---- K1 staging geometry (halo 1), f16 channel-pair cells ----
#define W1 18
#define WR1 19
#define CHS1P 346          // padded plane stride: 4*346%32==8 -> lhi offsets 0,8,16,24
// ---- K2 staging geometry (halo 4), f16 channel-pair cells ----
#define HALO 4
#define WIN 24
#define WROW 25
#define CHSP 602           // padded plane stride: 4*602%32==8 -> lhi offsets 0,8,16,24

typedef _Float16 h2 __attribute__((ext_vector_type(2)));
typedef __fp16  fp16v2 __attribute__((ext_vector_type(2)));
typedef _Float16 f16x8 __attribute__((ext_vector_type(8)));
typedef float    f32x4 __attribute__((ext_vector_type(4)));

__device__ __forceinline__ float dot2acc(unsigned int a, unsigned int b, float c) {
#if __has_builtin(__builtin_amdgcn_fdot2)
    return __builtin_amdgcn_fdot2(__builtin_bit_cast(h2, a),
                                  __builtin_bit_cast(h2, b), c, false);
#else
    h2 av = __builtin_bit_cast(h2, a), bv = __builtin_bit_cast(h2, b);
    return fmaf((float)av[0], (float)bv[0], fmaf((float)av[1], (float)bv[1], c));
#endif
}

__device__ __forceinline__ unsigned int packh2(float a, float b) {
#if __has_builtin(__builtin_amdgcn_cvt_pkrtz)
    fp16v2 r = __builtin_amdgcn_cvt_pkrtz(a, b);
    return __builtin_bit_cast(unsigned int, r);
#else
    h2 r; r[0] = (_Float16)a; r[1] = (_Float16)b;
    return __builtin_bit_cast(unsigned int, r);
#endif
}

__device__ __forceinline__ unsigned int packh2_rne(float a, float b) {
    h2 r; r[0] = (_Float16)a; r[1] = (_Float16)b;   // RNE casts
    return __builtin_bit_cast(unsigned int, r);
}

__device__ __forceinline__ h2 splat2(float a) {
    _Float16 h = (_Float16)a;
    h2 r; r[0] = h; r[1] = h;
    return r;
}

#define GEMV8(TP, S2) do {                                             \
    const uint4* _tp = (TP);                                           \
    _Pragma("unroll")                                                  \
    for (int q = 0; q < 8; ++q) {                                      \
        uint4 u = _tp[q];                                              \
        oacc[q * 4 + 0] = dot2acc((S2), u.x, oacc[q * 4 + 0]);         \
        oacc[q * 4 + 1] = dot2acc((S2), u.y, oacc[q * 4 + 1]);         \
        oacc[q * 4 + 2] = dot2acc((S2), u.z, oacc[q * 4 + 2]);         \
        oacc[q * 4 + 3] = dot2acc((S2), u.w, oacc[q * 4 + 3]);         \
    }                                                                  \
} while (0)

// tw_h layout (uint = h2 = channel pair): tw_h[((r*9 + k)*(CIN/2) + cp)*COUT + o]
__global__ void build_tw_kernel(const float* __restrict__ weight, unsigned int* __restrict__ tw_h) {
    int idx = blockIdx.x * blockDim.x + threadIdx.x; // 0..511
    if (idx >= COUT * (CIN / 2)) return;
    int o = idx & 31, cp = idx >> 5;

    float bb[2][9], w45[2][9];
    const float cs = 0.70710678f;
#pragma unroll
    for (int h = 0; h < 2; ++h) {
        int c = 2 * cp + h;
#pragma unroll
        for (int t = 0; t < 9; ++t) bb[h][t] = weight[(o * CIN + c) * 9 + t];
#pragma unroll
        for (int i = 0; i < 3; ++i) {
#pragma unroll
            for (int j = 0; j < 3; ++j) {
                float ys = cs * (float)(i - 1) + cs * (float)(j - 1) + 1.0f;
                float xs = -cs * (float)(i - 1) + cs * (float)(j - 1) + 1.0f;
                float y0f = floorf(ys), x0f = floorf(xs);
                float wy = ys - y0f, wx = xs - x0f;
                int iy0 = (int)y0f, ix0 = (int)x0f;
                float a = 0.0f;
#pragma unroll
                for (int dy = 0; dy < 2; ++dy) {
#pragma unroll
                    for (int dx = 0; dx < 2; ++dx) {
                        int iy = iy0 + dy, ix = ix0 + dx;
                        float wgt = (dy ? wy : 1.0f - wy) * (dx ? wx : 1.0f - wx);
                        bool valid = (iy >= 0) && (iy < 3) && (ix >= 0) && (ix < 3);
                        int iyc = min(max(iy, 0), 2), ixc = min(max(ix, 0), 2);
                        a += bb[h][iyc * 3 + ixc] * (valid ? wgt : 0.0f);
                    }
                }
                w45[h][i * 3 + j] = a;
            }
        }
    }

#pragma unroll
    for (int r = 0; r < NORI; ++r) {
        int rr = r & 3;
#pragma unroll
        for (int i = 0; i < 3; ++i) {
#pragma unroll
            for (int j = 0; j < 3; ++j) {
                int si, sj;
                if (rr == 0) { si = i;     sj = j;     }
                else if (rr == 1) { si = j;     sj = 2 - i; }
                else if (rr == 2) { si = 2 - i; sj = 2 - j; }
                else { si = 2 - j; sj = i;     }
                float v0 = (r < 4) ? bb[0][si * 3 + sj] : w45[0][si * 3 + sj];
                float v1 = (r < 4) ? bb[1][si * 3 + sj] : w45[1][si * 3 + sj];
                tw_h[(((r * 9) + (i * 3 + j)) * (CIN / 2) + cp) * COUT + o] =
                    packh2_rne(v0, v1);
            }
        }
    }
}

// Pack offset+mask conv weights in MFMA B-fragment layout:
// owmb[(kt*16 + cp)*32 + oc] = h2( w[oc][2cp][kt], w[oc][2cp+1][kt] ), oc>=27 -> 0
__global__ void pack_owmb_kernel(const float* __restrict__ offw, const float* __restrict__ mskw,
                                 unsigned int* __restrict__ owmb) {
    int idx = blockIdx.x * blockDim.x + threadIdx.x; // 9*16*32 = 4608
    if (idx >= 9 * 16 * 32) return;
    int oc = idx & 31;
    int cp = (idx >> 5) & 15;
    int kt = idx >> 9;
    float v0 = 0.0f, v1 = 0.0f;
    if (oc < 18) {
        v0 = offw[(oc * CIN + 2 * cp) * 9 + kt];
        v1 = offw[(oc * CIN + 2 * cp + 1) * 9 + kt];
    } else if (oc < 27) {
        v0 = mskw[((oc - 18) * CIN + 2 * cp) * 9 + kt];
        v1 = mskw[((oc - 18) * CIN + 2 * cp + 1) * 9 + kt];
    }
    owmb[(kt * 16 + cp) * 32 + oc] = packh2_rne(v0, v1);
}

// K1 (MFMA): unchanged from R16 (verified ~25us)
__global__ __launch_bounds__(256, 4) void offset_mask_mfma_kernel(
    const float* __restrict__ x,
    const unsigned int* __restrict__ owmb,
    const float* __restrict__ offb, const float* __restrict__ mskb,
    float* __restrict__ om)
{
    __shared__ unsigned int Lp[16 * CHS1P];   // 22144 B

    const int tiles_x = IMG / TS;
    int bid = (int)blockIdx.x;
    bid = (bid % 8) * (1024 / 8) + bid / 8;
    int bx = bid % tiles_x, by = bid / tiles_x;
    int tid = threadIdx.x;
    int y0w = by * TS - 1, x0w = bx * TS - 1;

    for (int i = tid; i < 16 * (W1 * W1); i += 256) {
        int pr = i / (W1 * W1), cell = i % (W1 * W1);
        int rr = cell / W1, cc = cell % W1;
        int gy = y0w + rr, gx = x0w + cc;
        float a = 0.0f, b = 0.0f;
        if ((unsigned)gy < (unsigned)IMG && (unsigned)gx < (unsigned)IMG) {
            const float* x0 = x + (2 * pr) * HW + gy * IMG + gx;
            a = x0[0]; b = x0[HW];
        }
        Lp[pr * CHS1P + rr * WR1 + cc] = packh2_rne(a, b);
    }
    __syncthreads();

    int lane = tid & 63, wid = tid >> 6;
    int lrow = lane & 15, lhi = lane >> 4;

    f32x4 acc[4][2] = {};

#pragma unroll
    for (int kt = 0; kt < 9; ++kt) {
        const int ky = kt / 3, kx = kt % 3;
        const unsigned int* tb = owmb + (kt * 16 + lhi * 4) * 32 + lrow;
        unsigned int bu0[4], bu1[4];
#pragma unroll
        for (int jj = 0; jj < 4; ++jj) {
            bu0[jj] = tb[jj * 32];
            bu1[jj] = tb[jj * 32 + 16];
        }
        uint4 b0q = make_uint4(bu0[0], bu0[1], bu0[2], bu0[3]);
        uint4 b1q = make_uint4(bu1[0], bu1[1], bu1[2], bu1[3]);
        f16x8 bf0 = __builtin_bit_cast(f16x8, b0q);
        f16x8 bf1 = __builtin_bit_cast(f16x8, b1q);

#pragma unroll
        for (int mt = 0; mt < 4; ++mt) {
            int yy = wid * 4 + mt;                       // pixel y, x = lrow
            int lq = (yy + ky) * WR1 + (lrow + kx);
            unsigned int au[4];
#pragma unroll
            for (int j = 0; j < 4; ++j)
                au[j] = Lp[(lhi * 4 + j) * CHS1P + lq];
            uint4 aq = make_uint4(au[0], au[1], au[2], au[3]);
            f16x8 af = __builtin_bit_cast(f16x8, aq);
            acc[mt][0] = __builtin_amdgcn_mfma_f32_16x16x32_f16(af, bf0, acc[mt][0], 0, 0, 0);
            acc[mt][1] = __builtin_amdgcn_mfma_f32_16x16x32_f16(af, bf1, acc[mt][1], 0, 0, 0);
        }
    }

    float bias_n0 = offb[lrow];
    float bias_n1 = (lrow < 2) ? offb[16 + lrow]
                  : ((lrow < 11) ? mskb[lrow - 2] : 0.0f);
    int Xs = bx * 16 + lhi * 4;
#pragma unroll
    for (int mt = 0; mt < 4; ++mt) {
        int Yg = by * 16 + wid * 4 + mt;
        {   // nt=0: oc 0..15 (offset channels); ch 8,9 forced 0
            int oc = lrow;
            float* op = om + oc * HW + Yg * IMG + Xs;
            bool zero = (oc == 8) || (oc == 9);
#pragma unroll
            for (int q = 0; q < 4; ++q)
                op[q] = zero ? 0.0f : (acc[mt][0][q] + bias_n0);
        }
        {   // nt=1: oc 16..26; >=18 mask channels (sigmoid), ch22 -> 0.5
            int oc = 16 + lrow;
            if (oc < 27) {
                float* op = om + oc * HW + Yg * IMG + Xs;
#pragma unroll
                for (int q = 0; q < 4; ++q) {
                    float t = acc[mt][1][q] + bias_n1;
                    if (oc >= 18) t = (oc == 22) ? 0.5f : 1.0f / (1.0f + __expf(-t));
                    op[q] = t;
                }
            }
        }
    }
}

// K2 (MFMA, v3): vs R16 — Wl/LQ LDS arrays deleted; consumer lanes recompute
// bilinear weights in-lane from om (L1/L2-hot, lhi-broadcast loads), sector id
// via tiny Rr[256]. LDS 46.6->39.0 KB -> 4 blocks/CU (16 waves, grid max),
// and the 6 per-group barriers disappear (one staging barrier total).
__global__ __launch_bounds__(256, 4) void deform_mfma_kernel(
    const float* __restrict__ x,
    const float* __restrict__ om,
    const float* __restrict__ gm,
    const unsigned int* __restrict__ tw_h,
    float* __restrict__ out)
{
    __shared__ unsigned int Lx[16 * CHSP];      // 38528 B
    __shared__ unsigned short Rr[256];          // 512 B: per-pixel sector
    __shared__ int flags[2];                    // [0]=rmask, [1]=anyslow

    const int tiles_x = IMG / TS;
    int bid = (int)blockIdx.x;
    bid = (bid % 8) * (1024 / 8) + bid / 8;
    int bx = bid % tiles_x, by = bid / tiles_x;
    int tid = threadIdx.x;
    int tx = tid & 15, ty = tid >> 4;
    int X = bx * TS + tx, Y = by * TS + ty;
    int p = Y * IMG + X;
    int y0w = by * TS - HALO, x0w = bx * TS - HALO;

    if (tid < 2) flags[tid] = 0;
    __syncthreads();

    // stage all 32 channels as f16 pairs (RNE), padded plane stride
    for (int i = tid; i < 16 * (WIN * WIN); i += 256) {
        int pr = i / (WIN * WIN), cell = i % (WIN * WIN);
        int rr = cell / WIN, cc = cell % WIN;
        int gy = y0w + rr, gx = x0w + cc;
        float a = 0.0f, b = 0.0f;
        if ((unsigned)gy < (unsigned)IMG && (unsigned)gx < (unsigned)IMG) {
            const float* x0 = x + (2 * pr) * HW + gy * IMG + gx;
            a = x0[0]; b = x0[HW];
        }
        Lx[pr * CHSP + rr * WROW + cc] = packh2_rne(a, b);
    }

    int r = 0;
#pragma unroll
    for (int n = 1; n < NORI; ++n) r = (gm[n * HW + p] > 0.5f) ? n : r;
    Rr[tid] = (unsigned short)r;

    // pre-pass: block-wide slow detection for all 9 taps
    bool slow = false;
    for (int kt = 0; kt < 9; ++kt) {
        int ky = kt / 3, kx = kt - ky * 3;
        float offy = om[(2 * kt) * HW + p];
        float offx = om[(2 * kt + 1) * HW + p];
        float pyf = (float)(Y - 1 + ky) + offy;
        float pxf = (float)(X - 1 + kx) + offx;
        int iy0 = (int)floorf(pyf), ix0 = (int)floorf(pxf);
        int ryu = iy0 - y0w, rxu = ix0 - x0w;
        slow |= !(((unsigned)ryu < (WIN - 1)) && ((unsigned)rxu < (WIN - 1)));
    }
    atomicOr(&flags[0], 1 << r);
    if (slow) flags[1] = 1;   // same-value race OK
    __syncthreads();

    int rmaskv = __builtin_amdgcn_readfirstlane(flags[0]);
    int anyslow = flags[1];

    if (anyslow) {
        // whole-block exact path (rare): per-thread f32, clamped global reads
        float oacc[32];
#pragma unroll
        for (int o = 0; o < 32; ++o) oacc[o] = 0.0f;
        for (int kt = 0; kt < 9; ++kt) {
            int ky = kt / 3, kx = kt - ky * 3;
            float offy = om[(2 * kt) * HW + p];
            float offx = om[(2 * kt + 1) * HW + p];
            float m    = om[(18 + kt) * HW + p];
            float pyf = (float)(Y - 1 + ky) + offy;
            float pxf = (float)(X - 1 + kx) + offx;
            float y0f = floorf(pyf), x0f = floorf(pxf);
            float wy = pyf - y0f, wx = pxf - x0f;
            int iy0 = (int)y0f, ix0 = (int)x0f;
            float vy0 = ((unsigned)iy0 < (unsigned)IMG) ? 1.0f : 0.0f;
            float vy1 = ((unsigned)(iy0 + 1) < (unsigned)IMG) ? 1.0f : 0.0f;
            float vx0 = ((unsigned)ix0 < (unsigned)IMG) ? 1.0f : 0.0f;
            float vx1 = ((unsigned)(ix0 + 1) < (unsigned)IMG) ? 1.0f : 0.0f;
            float w00 = m * (1.0f - wy) * (1.0f - wx) * vy0 * vx0;
            float w01 = m * (1.0f - wy) * wx * vy0 * vx1;
            float w10 = m * wy * (1.0f - wx) * vy1 * vx0;
            float w11 = m * wy * wx * vy1 * vx1;
            int cy0 = min(max(iy0, 0), IMG - 1), cy1 = min(max(iy0 + 1, 0), IMG - 1);
            int cx0 = min(max(ix0, 0), IMG - 1), cx1 = min(max(ix0 + 1, 0), IMG - 1);
            int g00 = cy0 * IMG + cx0, g01 = cy0 * IMG + cx1;
            int g10 = cy1 * IMG + cx0, g11 = cy1 * IMG + cx1;
            const uint4* tp = (const uint4*)(tw_h + (unsigned)((r * 9 + kt) * (CIN / 2)) * COUT);
            for (int cp = 0; cp < CIN / 2; ++cp) {
                const float* xc0 = x + (2 * cp) * HW;
                const float* xc1 = xc0 + HW;
                float s0 = fmaf(w00, xc0[g00], fmaf(w01, xc0[g01],
                           fmaf(w10, xc0[g10], w11 * xc0[g11])));
                float s1 = fmaf(w00, xc1[g00], fmaf(w01, xc1[g01],
                           fmaf(w10, xc1[g10], w11 * xc1[g11])));
                unsigned int s2 = packh2(s0, s1);
                GEMV8(tp + cp * 8, s2);
            }
        }
#pragma unroll
        for (int o = 0; o < 32; ++o) out[o * HW + p] = fmaxf(oacc[o], 0.0f);
        return;
    }

    // ---- MFMA path: in-lane per-Mtile bilinear setup, no Wl/LQ staging ----
    int lane = tid & 63, wid = tid >> 6;
    int lrow = lane & 15, lhi = lane >> 4;
    int Xg = bx * 16 + lrow;                  // consumed pixel x (A row = lane&15)

    f32x4 acc[4][2] = {};

    for (int kt = 0; kt < 9; ++kt) {
        int ky = kt / 3, kx = kt - ky * 3;
        // per-Mtile sampling setup in registers (statically indexed)
        h2 W00[4], W01[4], W10[4], W11[4];
        int LQv[4], Rv[4];
#pragma unroll
        for (int mt = 0; mt < 4; ++mt) {
            int pyg = by * 16 + wid * 4 + mt;
            int pg = pyg * IMG + Xg;
            int px = (wid * 4 + mt) * 16 + lrow;
            float offy = om[(2 * kt) * HW + pg];
            float offx = om[(2 * kt + 1) * HW + pg];
            float m    = om[(18 + kt) * HW + pg];
            float pyf = (float)(pyg - 1 + ky) + offy;
            float pxf = (float)(Xg - 1 + kx) + offx;
            float y0f = floorf(pyf), x0f = floorf(pxf);
            float wy = pyf - y0f, wx = pxf - x0f;
            int iy0 = (int)y0f, ix0 = (int)x0f;
            float vy0 = ((unsigned)iy0 < (unsigned)IMG) ? 1.0f : 0.0f;
            float vy1 = ((unsigned)(iy0 + 1) < (unsigned)IMG) ? 1.0f : 0.0f;
            float vx0 = ((unsigned)ix0 < (unsigned)IMG) ? 1.0f : 0.0f;
            float vx1 = ((unsigned)(ix0 + 1) < (unsigned)IMG) ? 1.0f : 0.0f;
            W00[mt] = splat2(m * (1.0f - wy) * (1.0f - wx) * vy0 * vx0);
            W01[mt] = splat2(m * (1.0f - wy) * wx * vy0 * vx1);
            W10[mt] = splat2(m * wy * (1.0f - wx) * vy1 * vx0);
            W11[mt] = splat2(m * wy * wx * vy1 * vx1);
            LQv[mt] = (iy0 - y0w) * WROW + (ix0 - x0w);
            Rv[mt]  = (int)Rr[px];
        }

        int rm = rmaskv;
        while (rm) {
            int rr = __ffs(rm) - 1;
            rm &= rm - 1;
            // B-fragments: lane o = lrow (+16 Ntile1), k = 8*lhi + b
            const unsigned int* tb = tw_h +
                (unsigned)((rr * 9 + kt) * (CIN / 2) + lhi * 4) * COUT + lrow;
            unsigned int bu0[4], bu1[4];
#pragma unroll
            for (int jj = 0; jj < 4; ++jj) {
                bu0[jj] = tb[jj * COUT];
                bu1[jj] = tb[jj * COUT + 16];
            }
            uint4 b0q = make_uint4(bu0[0], bu0[1], bu0[2], bu0[3]);
            uint4 b1q = make_uint4(bu1[0], bu1[1], bu1[2], bu1[3]);
            f16x8 bf0 = __builtin_bit_cast(f16x8, b0q);
            f16x8 bf1 = __builtin_bit_cast(f16x8, b1q);

#pragma unroll
            for (int mt = 0; mt < 4; ++mt) {
                unsigned int keep = (Rv[mt] == rr) ? 0xFFFFFFFFu : 0u;
                int lq = LQv[mt];
                unsigned int au[4];
#pragma unroll
                for (int j = 0; j < 4; ++j) {          // channel pairs 4*lhi+j
                    int lb = (lhi * 4 + j) * CHSP + lq;
                    h2 v00 = __builtin_bit_cast(h2, Lx[lb]);
                    h2 v01 = __builtin_bit_cast(h2, Lx[lb + 1]);
                    h2 v10 = __builtin_bit_cast(h2, Lx[lb + WROW]);
                    h2 v11 = __builtin_bit_cast(h2, Lx[lb + WROW + 1]);
                    h2 s = W00[mt] * v00 + W01[mt] * v01 + W10[mt] * v10 + W11[mt] * v11;
                    au[j] = __builtin_bit_cast(unsigned int, s) & keep;
                }
                uint4 aq = make_uint4(au[0], au[1], au[2], au[3]);
                f16x8 af = __builtin_bit_cast(f16x8, aq);
                acc[mt][0] = __builtin_amdgcn_mfma_f32_16x16x32_f16(af, bf0, acc[mt][0], 0, 0, 0);
                acc[mt][1] = __builtin_amdgcn_mfma_f32_16x16x32_f16(af, bf1, acc[mt][1], 0, 0, 0);
            }
        }
    }

    // epilogue: D col = o (lane&15 / +16), row = pixel x = 4*lhi+q
    int Xs = bx * 16 + lhi * 4;
#pragma unroll
    for (int mt = 0; mt < 4; ++mt) {
        int Yg = by * 16 + wid * 4 + mt;
#pragma unroll
        for (int nt = 0; nt < 2; ++nt) {
            float* op = out + (nt * 16 + lrow) * HW + Yg * IMG + Xs;
#pragma unroll
            for (int q = 0; q < 4; ++q)
                op[q] = fmaxf(acc[mt][nt][q], 0.0f);
        }
    }
}

extern "C" void kernel_launch(void* const* d_in, const int* in_sizes, int n_in,
                              void* d_out, int out_size, void* d_ws, size_t ws_size,
                              hipStream_t stream) {
    const float* x      = (const float*)d_in[0];
    const float* weight = (const float*)d_in[1];
    const float* offw   = (const float*)d_in[2];
    const float* offb   = (const float*)d_in[3];
    const float* mskw   = (const float*)d_in[4];
    const float* mskb   = (const float*)d_in[5];
    const float* gm     = (const float*)d_in[6];
    float* out = (float*)d_out;

    unsigned int* tw_h = (unsigned int*)d_ws;                   // 147456 B
    unsigned int* owmb = (unsigned int*)((char*)d_ws + 147456); // 18432 B
    float* om = (float*)((char*)d_ws + 294912);                 // 27*HW*4 = 28.3 MB

    build_tw_kernel<<<2, 256, 0, stream>>>(weight, tw_h);
    pack_owmb_kernel<<<18, 256, 0, stream>>>(offw, mskw, owmb);

    const int tiles = (IMG / TS) * (IMG / TS); // 1024
    offset_mask_mfma_kernel<<<tiles, 256, 0, stream>>>(x, owmb, offb, mskb, om);
    deform_mfma_kernel<<<tiles, 256, 0, stream>>>(x, om, gm, tw_h, out);
}